// Round 1
// baseline (320.740 us; speedup 1.0000x reference)
//
#include <hip/hip_runtime.h>

// Problem: B=2, L=4096, D_IN=512, H=8, D_K=D_V=64, D_OUT=512, all fp32.
// out[b] = x[b] @ C[b],  C[b] = sum_h Wq[h] (Wk[h]^T G[b] Wv[h]) Wo[h],
// G[b] = x[b]^T x[b].   (valid because there is no softmax)

#define BDIM 2
#define LDIM 4096
#define DIN 512
#define HDIM 8
#define DK 64
#define DV 64
#define DOUT 512

#define TILE 64
#define BK 16
#define NS 8  // split-K slices for the Gram kernel

// ---------------- inner compute shared by all kernels ----------------
// As[kk][m] = A(m, k0+kk), Bs[kk][n] = B(k0+kk, n); acc(m,n) += A·B
#define INNER_LOOP                                            \
    _Pragma("unroll")                                         \
    for (int kk = 0; kk < BK; ++kk) {                         \
        float4 a4 = *(const float4*)&As[kk][ty * 4];          \
        float4 b4 = *(const float4*)&Bs[kk][tx * 4];          \
        float ar[4] = {a4.x, a4.y, a4.z, a4.w};               \
        float br[4] = {b4.x, b4.y, b4.z, b4.w};               \
        _Pragma("unroll")                                     \
        for (int i = 0; i < 4; ++i)                           \
            _Pragma("unroll")                                 \
            for (int j = 0; j < 4; ++j)                       \
                acc[i][j] += ar[i] * br[j];                   \
    }

// ---- K1: G[b] = x[b]^T x[b], split-K over L (atomicAdd), G pre-zeroed ----
__global__ __launch_bounds__(256) void gram_kernel(const float* __restrict__ x,
                                                   float* __restrict__ G) {
    __shared__ float As[BK][TILE];
    __shared__ float Bs[BK][TILE];
    const int i0 = blockIdx.x * TILE;
    const int j0 = blockIdx.y * TILE;
    const int b = blockIdx.z / NS;
    const int slice = blockIdx.z % NS;
    const int t = threadIdx.x, tx = t & 15, ty = t >> 4;
    const int lr = t >> 4, lc = (t & 15) * 4;  // natural 16x64 tile load
    const int l_base = slice * (LDIM / NS);
    const float* xb = x + (size_t)b * LDIM * DIN;
    float acc[4][4] = {};
    for (int l0 = 0; l0 < LDIM / NS; l0 += BK) {
        const float* xrow = xb + (size_t)(l_base + l0 + lr) * DIN;
        float4 av = *(const float4*)(xrow + i0 + lc);
        float4 bv = *(const float4*)(xrow + j0 + lc);
        *(float4*)&As[lr][lc] = av;
        *(float4*)&Bs[lr][lc] = bv;
        __syncthreads();
        INNER_LOOP
        __syncthreads();
    }
    float* Gb = G + (size_t)b * DIN * DIN;
#pragma unroll
    for (int i = 0; i < 4; ++i)
#pragma unroll
        for (int j = 0; j < 4; ++j)
            atomicAdd(&Gb[(size_t)(i0 + ty * 4 + i) * DIN + j0 + tx * 4 + j], acc[i][j]);
}

// ---- K2a: U[b,h] = G[b] @ Wv[h]  (512x512 @ 512x64) ----
__global__ __launch_bounds__(256) void proj_v_kernel(const float* __restrict__ G,
                                                     const float* __restrict__ Wv,
                                                     float* __restrict__ U) {
    __shared__ float As[BK][TILE];
    __shared__ float Bs[BK][TILE];
    const int i0 = blockIdx.x * TILE, h = blockIdx.y, b = blockIdx.z;
    const int t = threadIdx.x, tx = t & 15, ty = t >> 4;
    const int am = t >> 2, ak = (t & 3) * 4;   // transpose-load for A
    const int br_ = t >> 4, bc = (t & 15) * 4; // natural load for B
    const float* Gb = G + (size_t)b * DIN * DIN;
    const float* Wvh = Wv + (size_t)h * DIN * DV;
    float acc[4][4] = {};
    for (int k0 = 0; k0 < DIN; k0 += BK) {
        float4 av = *(const float4*)(Gb + (size_t)(i0 + am) * DIN + k0 + ak);
        As[ak + 0][am] = av.x; As[ak + 1][am] = av.y;
        As[ak + 2][am] = av.z; As[ak + 3][am] = av.w;
        *(float4*)&Bs[br_][bc] = *(const float4*)(Wvh + (size_t)(k0 + br_) * DV + bc);
        __syncthreads();
        INNER_LOOP
        __syncthreads();
    }
    float* Ubh = U + (size_t)(b * HDIM + h) * DIN * DV;
#pragma unroll
    for (int i = 0; i < 4; ++i)
#pragma unroll
        for (int j = 0; j < 4; ++j)
            Ubh[(size_t)(i0 + ty * 4 + i) * DV + tx * 4 + j] = acc[i][j];
}

// ---- K2b: M[b,h] = Wk[h]^T @ U[b,h]  (64x512^T @ 512x64 -> 64x64) ----
__global__ __launch_bounds__(256) void kv_gram_kernel(const float* __restrict__ Wk,
                                                      const float* __restrict__ U,
                                                      float* __restrict__ M) {
    __shared__ float As[BK][TILE];
    __shared__ float Bs[BK][TILE];
    const int h = blockIdx.x, b = blockIdx.y;
    const int t = threadIdx.x, tx = t & 15, ty = t >> 4;
    const int lr = t >> 4, lc = (t & 15) * 4;
    const float* Wkh = Wk + (size_t)h * DIN * DK;
    const float* Ubh = U + (size_t)(b * HDIM + h) * DIN * DV;
    float acc[4][4] = {};
    for (int i0 = 0; i0 < DIN; i0 += BK) {
        // reduction dim is the row dim of both operands -> both natural loads
        *(float4*)&As[lr][lc] = *(const float4*)(Wkh + (size_t)(i0 + lr) * DK + lc);
        *(float4*)&Bs[lr][lc] = *(const float4*)(Ubh + (size_t)(i0 + lr) * DV + lc);
        __syncthreads();
        INNER_LOOP
        __syncthreads();
    }
    float* Mbh = M + (size_t)(b * HDIM + h) * DK * DV;
#pragma unroll
    for (int i = 0; i < 4; ++i)
#pragma unroll
        for (int j = 0; j < 4; ++j)
            Mbh[(size_t)(ty * 4 + i) * DV + tx * 4 + j] = acc[i][j];
}

// ---- K2c: A[b][i][h*64+v] = (Wq[h] @ M[b,h])[i][v]  (512x64 @ 64x64) ----
__global__ __launch_bounds__(256) void qm_kernel(const float* __restrict__ Wq,
                                                 const float* __restrict__ M,
                                                 float* __restrict__ Aout) {
    __shared__ float As[BK][TILE];
    __shared__ float Bs[BK][TILE];
    const int i0 = blockIdx.x * TILE, h = blockIdx.y, b = blockIdx.z;
    const int t = threadIdx.x, tx = t & 15, ty = t >> 4;
    const int am = t >> 2, ak = (t & 3) * 4;
    const int br_ = t >> 4, bc = (t & 15) * 4;
    const float* Wqh = Wq + (size_t)h * DIN * DK;
    const float* Mbh = M + (size_t)(b * HDIM + h) * DK * DV;
    float acc[4][4] = {};
    for (int k0 = 0; k0 < DK; k0 += BK) {
        float4 av = *(const float4*)(Wqh + (size_t)(i0 + am) * DK + k0 + ak);
        As[ak + 0][am] = av.x; As[ak + 1][am] = av.y;
        As[ak + 2][am] = av.z; As[ak + 3][am] = av.w;
        *(float4*)&Bs[br_][bc] = *(const float4*)(Mbh + (size_t)(k0 + br_) * DV + bc);
        __syncthreads();
        INNER_LOOP
        __syncthreads();
    }
    // A laid out [b][i(512)][h*64+v] -> row length 512
    float* Ab = Aout + (size_t)b * DIN * (HDIM * DV);
#pragma unroll
    for (int i = 0; i < 4; ++i)
#pragma unroll
        for (int j = 0; j < 4; ++j)
            Ab[(size_t)(i0 + ty * 4 + i) * (HDIM * DV) + h * DV + tx * 4 + j] = acc[i][j];
}

// ---- K2d: C[b] = A[b] @ Wo_flat  (512x512 @ 512x512) ----
__global__ __launch_bounds__(256) void aw_kernel(const float* __restrict__ Aout,
                                                 const float* __restrict__ Wo,
                                                 float* __restrict__ C) {
    __shared__ float As[BK][TILE];
    __shared__ float Bs[BK][TILE];
    const int i0 = blockIdx.x * TILE, o0 = blockIdx.y * TILE, b = blockIdx.z;
    const int t = threadIdx.x, tx = t & 15, ty = t >> 4;
    const int am = t >> 2, ak = (t & 3) * 4;
    const int br_ = t >> 4, bc = (t & 15) * 4;
    const float* Ab = Aout + (size_t)b * DIN * DIN;
    float acc[4][4] = {};
    for (int k0 = 0; k0 < DIN; k0 += BK) {
        float4 av = *(const float4*)(Ab + (size_t)(i0 + am) * DIN + k0 + ak);
        As[ak + 0][am] = av.x; As[ak + 1][am] = av.y;
        As[ak + 2][am] = av.z; As[ak + 3][am] = av.w;
        *(float4*)&Bs[br_][bc] = *(const float4*)(Wo + (size_t)(k0 + br_) * DOUT + o0 + bc);
        __syncthreads();
        INNER_LOOP
        __syncthreads();
    }
    float* Cb = C + (size_t)b * DIN * DOUT;
#pragma unroll
    for (int i = 0; i < 4; ++i)
#pragma unroll
        for (int j = 0; j < 4; ++j)
            Cb[(size_t)(i0 + ty * 4 + i) * DOUT + o0 + tx * 4 + j] = acc[i][j];
}

// ---- K3: out[b] = x[b] @ C[b]  (4096x512 @ 512x512) ----
__global__ __launch_bounds__(256) void out_kernel(const float* __restrict__ x,
                                                  const float* __restrict__ C,
                                                  float* __restrict__ out) {
    __shared__ float As[BK][TILE];
    __shared__ float Bs[BK][TILE];
    const int o0 = blockIdx.x * TILE, l0 = blockIdx.y * TILE, b = blockIdx.z;
    const int t = threadIdx.x, tx = t & 15, ty = t >> 4;
    const int am = t >> 2, ak = (t & 3) * 4;
    const int br_ = t >> 4, bc = (t & 15) * 4;
    const float* xb = x + (size_t)b * LDIM * DIN;
    const float* Cb = C + (size_t)b * DIN * DOUT;
    float acc[4][4] = {};
    for (int k0 = 0; k0 < DIN; k0 += BK) {
        float4 av = *(const float4*)(xb + (size_t)(l0 + am) * DIN + k0 + ak);
        As[ak + 0][am] = av.x; As[ak + 1][am] = av.y;
        As[ak + 2][am] = av.z; As[ak + 3][am] = av.w;
        *(float4*)&Bs[br_][bc] = *(const float4*)(Cb + (size_t)(k0 + br_) * DOUT + o0 + bc);
        __syncthreads();
        INNER_LOOP
        __syncthreads();
    }
    float* outb = out + (size_t)b * LDIM * DOUT;
#pragma unroll
    for (int i = 0; i < 4; ++i)
#pragma unroll
        for (int j = 0; j < 4; ++j)
            outb[(size_t)(l0 + ty * 4 + i) * DOUT + o0 + tx * 4 + j] = acc[i][j];
}

extern "C" void kernel_launch(void* const* d_in, const int* in_sizes, int n_in,
                              void* d_out, int out_size, void* d_ws, size_t ws_size,
                              hipStream_t stream) {
    const float* x  = (const float*)d_in[0];
    const float* Wq = (const float*)d_in[1];
    const float* Wk = (const float*)d_in[2];
    const float* Wv = (const float*)d_in[3];
    const float* Wo = (const float*)d_in[4];
    float* out = (float*)d_out;

    // workspace layout (floats)
    float* G    = (float*)d_ws;                       // 2*512*512
    float* U    = G    + (size_t)BDIM * DIN * DIN;    // 2*8*512*64
    float* M    = U    + (size_t)BDIM * HDIM * DIN * DV;  // 2*8*64*64
    float* Aout = M    + (size_t)BDIM * HDIM * DK * DV;   // 2*512*512
    float* C    = Aout + (size_t)BDIM * DIN * DIN;    // 2*512*512

    // zero G (atomic accumulation target)
    hipMemsetAsync(G, 0, (size_t)BDIM * DIN * DIN * sizeof(float), stream);

    gram_kernel<<<dim3(DIN / TILE, DIN / TILE, BDIM * NS), 256, 0, stream>>>(x, G);
    proj_v_kernel<<<dim3(DIN / TILE, HDIM, BDIM), 256, 0, stream>>>(G, Wv, U);
    kv_gram_kernel<<<dim3(HDIM, BDIM), 256, 0, stream>>>(Wk, U, M);
    qm_kernel<<<dim3(DIN / TILE, HDIM, BDIM), 256, 0, stream>>>(Wq, M, Aout);
    aw_kernel<<<dim3(DIN / TILE, DOUT / TILE, BDIM), 256, 0, stream>>>(Aout, Wo, C);
    out_kernel<<<dim3(DOUT / TILE, LDIM / TILE, BDIM), 256, 0, stream>>>(x, C, out);
}

// Round 2
// 198.752 us; speedup vs baseline: 1.6138x; 1.6138x over previous
//
#include <hip/hip_runtime.h>
#include <cstdint>

// out[b] = x[b] @ C[b],  C[b] = sum_h Wq[h] (Wk[h]^T G[b] Wv[h]) Wo[h],
// G[b] = x[b]^T x[b].  All heavy GEMMs in bf16 MFMA (16x16x32), fp32 accum.
// Error budget: threshold ~2% of max|ref| (9.0e9 vs max|ref| 4.5e11); bf16
// chain expected ~0.5-1%.

#define BDIM 2
#define LDIM 4096
#define DIN 512
#define HDIM 8
#define DK 64
#define DV 64
#define DOUT 512

using bf16_t = __bf16;
typedef __bf16 bf16x8 __attribute__((ext_vector_type(8)));
typedef float floatx4 __attribute__((ext_vector_type(4)));

__device__ __forceinline__ unsigned short f2bf(float f) {
    unsigned int u = __builtin_bit_cast(unsigned int, f);
    u += 0x7FFFu + ((u >> 16) & 1u);   // round-to-nearest-even
    return (unsigned short)(u >> 16);
}

__device__ __forceinline__ void gld_lds16(const void* g, void* l) {
    __builtin_amdgcn_global_load_lds(
        (const __attribute__((address_space(1))) void*)g,
        (__attribute__((address_space(3))) void*)l, 16, 0, 0);
}

// ---------------- generic TN MFMA GEMM core ----------------
// C[m][n] = sum_k A[m][k] * B[n][k]; A: M x K (lda), B: N x K (ldb), both
// k-contiguous bf16. 256 threads, 2x2 waves, each wave FMxFN 16x16 frags.
// Output: natural C[m*ldc+n] or transposed C[n*ldc+m]; bf16 or fp32.
template <int BM, int BN, bool TRANS_OUT, bool OUT_BF16>
__device__ __forceinline__ void gemm_core(const bf16_t* A, const bf16_t* B,
                                          void* Cp, int K, int lda, int ldb,
                                          int ldc, int tm, int tn) {
    constexpr int BK = 32;
    constexpr int WM = BM / 2, WN = BN / 2;
    constexpr int FM = WM / 16, FN = WN / 16;
    __shared__ bf16_t As[BM * BK];
    __shared__ bf16_t Bs[BN * BK];
    const int tid = threadIdx.x;
    const int lane = tid & 63;
    const int wr = (tid >> 7) & 1;
    const int wc = (tid >> 6) & 1;

    A += (size_t)tm * lda;
    B += (size_t)tn * ldb;

    floatx4 acc[FM][FN] = {};

    for (int k0 = 0; k0 < K; k0 += BK) {
        // stage A tile (BM x 32) via direct-to-LDS 16B loads
#pragma unroll
        for (int i = 0; i < (BM * 4) / 256; ++i) {
            int c = i * 256 + tid;          // 16B chunk index
            int m = c >> 2, kc = c & 3;     // 4 chunks per 32-elem row
            gld_lds16(A + (size_t)m * lda + k0 + kc * 8, As + c * 8);
        }
#pragma unroll
        for (int i = 0; i < (BN * 4) / 256; ++i) {
            int c = i * 256 + tid;
            int m = c >> 2, kc = c & 3;
            gld_lds16(B + (size_t)m * ldb + k0 + kc * 8, Bs + c * 8);
        }
        __syncthreads();

        bf16x8 aF[FM], bF[FN];
#pragma unroll
        for (int fm = 0; fm < FM; ++fm)
            aF[fm] = *(const bf16x8*)(As + (wr * WM + fm * 16 + (lane & 15)) * BK +
                                      (lane >> 4) * 8);
#pragma unroll
        for (int fn = 0; fn < FN; ++fn)
            bF[fn] = *(const bf16x8*)(Bs + (wc * WN + fn * 16 + (lane & 15)) * BK +
                                      (lane >> 4) * 8);
#pragma unroll
        for (int fm = 0; fm < FM; ++fm)
#pragma unroll
            for (int fn = 0; fn < FN; ++fn)
                acc[fm][fn] = __builtin_amdgcn_mfma_f32_16x16x32_bf16(
                    aF[fm], bF[fn], acc[fm][fn], 0, 0, 0);
        __syncthreads();
    }

    // epilogue: C/D map col=lane&15, row=(lane>>4)*4+reg
    const int cr4 = (lane >> 4) * 4;
    const int cn = lane & 15;
#pragma unroll
    for (int fm = 0; fm < FM; ++fm)
#pragma unroll
        for (int fn = 0; fn < FN; ++fn)
#pragma unroll
            for (int r = 0; r < 4; ++r) {
                int m = tm + wr * WM + fm * 16 + cr4 + r;
                int n = tn + wc * WN + fn * 16 + cn;
                size_t idx = TRANS_OUT ? ((size_t)n * ldc + m)
                                       : ((size_t)m * ldc + n);
                if (OUT_BF16)
                    ((unsigned short*)Cp)[idx] = f2bf(acc[fm][fn][r]);
                else
                    ((float*)Cp)[idx] = acc[fm][fn][r];
            }
}

// ---------------- GEMM wrappers ----------------
// G[b] = xT[b] @ xT[b]^T  (512x512, K=4096), out bf16 natural (symmetric)
__global__ __launch_bounds__(256) void k_gram(const bf16_t* xT, unsigned short* G16) {
    int b = blockIdx.z;
    const bf16_t* Ab = xT + (size_t)b * DIN * LDIM;
    gemm_core<128, 128, false, true>(Ab, Ab, G16 + (size_t)b * DIN * DIN, LDIM,
                                     LDIM, LDIM, DIN, blockIdx.x * 128,
                                     blockIdx.y * 128);
}

// UT[b,h][v][i] = (G[b] @ Wv[h])^T : A=G16 (512xK512), B=WvT[h] (64xK512)
__global__ __launch_bounds__(256) void k_proj(const bf16_t* G16, const bf16_t* WvT,
                                              unsigned short* UT) {
    int z = blockIdx.z, b = z >> 3, h = z & 7;
    gemm_core<128, 64, true, true>(G16 + (size_t)b * DIN * DIN,
                                   WvT + (size_t)h * DV * DIN,
                                   UT + (size_t)z * DV * DIN, DIN, DIN, DIN,
                                   DIN, blockIdx.x * 128, 0);
}

// MT[b,h][v][dk] = (Wk[h]^T G Wv[h])^T : A=WkT[h] (64xK512), B=UT (64xK512)
__global__ __launch_bounds__(256) void k_kv(const bf16_t* WkT, const bf16_t* UT,
                                            unsigned short* MT) {
    int z = blockIdx.z, h = z & 7;
    gemm_core<64, 64, true, true>(WkT + (size_t)h * DK * DIN,
                                  UT + (size_t)z * DV * DIN,
                                  MT + (size_t)z * DK * DV, DIN, DIN, DIN, DV,
                                  0, 0);
}

// Aout[b][i][h*64+v] = Wq[h] @ M[b,h] : A=Wq16[h] (512xK64), B=MT (64xK64)
__global__ __launch_bounds__(256) void k_qm(const bf16_t* Wq16, const bf16_t* MT,
                                            unsigned short* Aout) {
    int z = blockIdx.z, b = z >> 3, h = z & 7;
    gemm_core<128, 64, false, true>(Wq16 + (size_t)h * DIN * DK,
                                    MT + (size_t)z * DK * DV,
                                    Aout + (size_t)b * DIN * DIN + h * DV, DK,
                                    DK, DK, DIN, blockIdx.x * 128, 0);
}

// CT[b][o][i] = (Aout[b] @ Wo_flat)^T : A=Aout (512xK512), B=WoT (512xK512)
__global__ __launch_bounds__(256) void k_aw(const bf16_t* Aout, const bf16_t* WoT,
                                            unsigned short* CT) {
    int b = blockIdx.z;
    gemm_core<128, 128, true, true>(Aout + (size_t)b * DIN * DIN, WoT,
                                    CT + (size_t)b * DIN * DOUT, DIN, DIN, DIN,
                                    DIN, blockIdx.x * 128, blockIdx.y * 128);
}

// out[b][l][o] = x16[b] @ C[b] : A=x16 (4096xK512), B=CT (512xK512), fp32 out
__global__ __launch_bounds__(256) void k_out(const bf16_t* x16, const bf16_t* CT,
                                             float* out) {
    int b = blockIdx.z;
    gemm_core<128, 128, false, false>(x16 + (size_t)b * LDIM * DIN,
                                      CT + (size_t)b * DIN * DOUT,
                                      out + (size_t)b * LDIM * DOUT, DIN, DIN,
                                      DIN, DOUT, blockIdx.x * 128,
                                      blockIdx.y * 128);
}

// ---------------- prep kernels ----------------
// x -> xb (bf16 natural [b][l][d]) and xT (bf16 [b][d][l])
__global__ __launch_bounds__(256) void k_convx(const float* x, unsigned short* xb,
                                               unsigned short* xT) {
    __shared__ unsigned short T[64][65];
    int b = blockIdx.z, l0 = blockIdx.y * 64, d0 = blockIdx.x * 64;
    int tr = threadIdx.x >> 4, tc4 = (threadIdx.x & 15) * 4;
    const float* xp = x + (size_t)b * LDIM * DIN;
    unsigned short* xbp = xb + (size_t)b * LDIM * DIN;
#pragma unroll
    for (int p = 0; p < 4; ++p) {
        int l = p * 16 + tr;
        float4 v = *(const float4*)(xp + (size_t)(l0 + l) * DIN + d0 + tc4);
        unsigned short q0 = f2bf(v.x), q1 = f2bf(v.y), q2 = f2bf(v.z), q3 = f2bf(v.w);
        *(ushort4*)(xbp + (size_t)(l0 + l) * DIN + d0 + tc4) =
            make_ushort4(q0, q1, q2, q3);
        T[l][tc4 + 0] = q0; T[l][tc4 + 1] = q1;
        T[l][tc4 + 2] = q2; T[l][tc4 + 3] = q3;
    }
    __syncthreads();
    unsigned short* xTp = xT + (size_t)b * DIN * LDIM;
#pragma unroll
    for (int p = 0; p < 4; ++p) {
        int d = p * 16 + tr;
        ushort4 u = make_ushort4(T[tc4 + 0][d], T[tc4 + 1][d], T[tc4 + 2][d],
                                 T[tc4 + 3][d]);
        *(ushort4*)(xTp + (size_t)(d0 + d) * LDIM + l0 + tc4) = u;
    }
}

// dst[bt][c][r] = bf16(src[bt][r][c]); rows, cols multiples of 64
__global__ __launch_bounds__(256) void k_tconv(const float* src, unsigned short* dst,
                                               int rows, int cols) {
    __shared__ unsigned short T[64][65];
    int bt = blockIdx.z, r0 = blockIdx.y * 64, c0 = blockIdx.x * 64;
    src += (size_t)bt * rows * cols;
    dst += (size_t)bt * rows * cols;
    int tr = threadIdx.x >> 4, tc4 = (threadIdx.x & 15) * 4;
#pragma unroll
    for (int p = 0; p < 4; ++p) {
        int r = p * 16 + tr;
        float4 v = *(const float4*)(src + (size_t)(r0 + r) * cols + c0 + tc4);
        T[r][tc4 + 0] = f2bf(v.x); T[r][tc4 + 1] = f2bf(v.y);
        T[r][tc4 + 2] = f2bf(v.z); T[r][tc4 + 3] = f2bf(v.w);
    }
    __syncthreads();
#pragma unroll
    for (int p = 0; p < 4; ++p) {
        int c = p * 16 + tr;
        ushort4 u = make_ushort4(T[tc4 + 0][c], T[tc4 + 1][c], T[tc4 + 2][c],
                                 T[tc4 + 3][c]);
        *(ushort4*)(dst + (size_t)(c0 + c) * rows + r0 + tc4) = u;
    }
}

// plain fp32 -> bf16 convert (Wq), n multiple of 1024
__global__ __launch_bounds__(256) void k_conv(const float* src, unsigned short* dst) {
    int g = blockIdx.x * 256 + threadIdx.x;
    float4 v = *(const float4*)(src + (size_t)g * 4);
    *(ushort4*)(dst + (size_t)g * 4) =
        make_ushort4(f2bf(v.x), f2bf(v.y), f2bf(v.z), f2bf(v.w));
}

extern "C" void kernel_launch(void* const* d_in, const int* in_sizes, int n_in,
                              void* d_out, int out_size, void* d_ws, size_t ws_size,
                              hipStream_t stream) {
    const float* x  = (const float*)d_in[0];
    const float* Wq = (const float*)d_in[1];
    const float* Wk = (const float*)d_in[2];
    const float* Wv = (const float*)d_in[3];
    const float* Wo = (const float*)d_in[4];
    float* out = (float*)d_out;

    // workspace carve-up (ushort elements), ~23 MB total
    unsigned short* w = (unsigned short*)d_ws;
    unsigned short* xb16 = w;                 w += (size_t)BDIM * LDIM * DIN;  // 4 Mi
    unsigned short* xT16 = w;                 w += (size_t)BDIM * DIN * LDIM;  // 4 Mi
    unsigned short* Wq16 = w;                 w += (size_t)HDIM * DIN * DK;
    unsigned short* WkT  = w;                 w += (size_t)HDIM * DK * DIN;
    unsigned short* WvT  = w;                 w += (size_t)HDIM * DV * DIN;
    unsigned short* WoT  = w;                 w += (size_t)DOUT * HDIM * DV;
    unsigned short* G16  = w;                 w += (size_t)BDIM * DIN * DIN;
    unsigned short* UT   = w;                 w += (size_t)BDIM * HDIM * DV * DIN;
    unsigned short* MT   = w;                 w += (size_t)BDIM * HDIM * DK * DV;
    unsigned short* Aout = w;                 w += (size_t)BDIM * DIN * DIN;
    unsigned short* CT   = w;                 w += (size_t)BDIM * DIN * DOUT;

    // prep
    k_convx<<<dim3(DIN / 64, LDIM / 64, BDIM), 256, 0, stream>>>(x, xb16, xT16);
    k_conv<<<dim3((HDIM * DIN * DK) / 1024), 256, 0, stream>>>(Wq, Wq16);
    k_tconv<<<dim3(1, 8, HDIM), 256, 0, stream>>>(Wk, WkT, DIN, DK);
    k_tconv<<<dim3(1, 8, HDIM), 256, 0, stream>>>(Wv, WvT, DIN, DV);
    k_tconv<<<dim3(8, 8, 1), 256, 0, stream>>>(Wo, WoT, HDIM * DV, DOUT);

    // GEMM chain
    k_gram<<<dim3(4, 4, BDIM), 256, 0, stream>>>((const bf16_t*)xT16, G16);
    k_proj<<<dim3(4, 1, BDIM * HDIM), 256, 0, stream>>>((const bf16_t*)G16,
                                                        (const bf16_t*)WvT, UT);
    k_kv<<<dim3(1, 1, BDIM * HDIM), 256, 0, stream>>>((const bf16_t*)WkT,
                                                      (const bf16_t*)UT, MT);
    k_qm<<<dim3(4, 1, BDIM * HDIM), 256, 0, stream>>>((const bf16_t*)Wq16,
                                                      (const bf16_t*)MT, Aout);
    k_aw<<<dim3(4, 4, BDIM), 256, 0, stream>>>((const bf16_t*)Aout,
                                               (const bf16_t*)WoT, CT);
    k_out<<<dim3(LDIM / 128, DOUT / 128, BDIM), 256, 0, stream>>>(
        (const bf16_t*)xb16, (const bf16_t*)CT, out);
}

// Round 3
// 162.546 us; speedup vs baseline: 1.9732x; 1.2227x over previous
//
#include <hip/hip_runtime.h>
#include <cstdint>

// out[b] = x[b] @ C[b],  C[b] = sum_h Wq[h] (Wk[h]^T G[b] Wv[h]) Wo[h],
// G[b] = x[b]^T x[b].  bf16 MFMA 16x16x32, fp32 accum.
// R3: split-K gram (512 blocks, fp32 atomics); middle chain re-batched:
//   U_all[b] = G[b] @ Wv_cat                  (dense 512^3 per b)
//   M[b,h]   = Wk[h]^T @ U[b,h]               (16 x 64x64 batched)
//   N[b,h]   = M[b,h] @ Wo[h]  (stored NT)    (128 blocks)
//   C[b]     = Wq_cat @ vstack_h N[b,h]       (dense 512^3 per b)
//   out[b]   = x[b] @ C[b]

#define BDIM 2
#define LDIM 4096
#define DIN 512
#define HDIM 8
#define DK 64
#define DV 64
#define DOUT 512
#define NS 16  // split-K slices for gram

using bf16_t = __bf16;
typedef __bf16 bf16x8 __attribute__((ext_vector_type(8)));
typedef float floatx4 __attribute__((ext_vector_type(4)));

__device__ __forceinline__ unsigned short f2bf(float f) {
    unsigned int u = __builtin_bit_cast(unsigned int, f);
    u += 0x7FFFu + ((u >> 16) & 1u);
    return (unsigned short)(u >> 16);
}

__device__ __forceinline__ void gld_lds16(const void* g, void* l) {
    __builtin_amdgcn_global_load_lds(
        (const __attribute__((address_space(1))) void*)g,
        (__attribute__((address_space(3))) void*)l, 16, 0, 0);
}

// ---------------- generic TN MFMA GEMM core ----------------
// C[m][n] = sum_k A[m][k]*B[n][k]; A,B k-contiguous bf16. 256 thr, 2x2 waves.
// OUT_MODE: 0 = f32 store, 1 = bf16 store, 2 = f32 atomicAdd.
template <int BM, int BN, bool TRANS_OUT, int OUT_MODE>
__device__ __forceinline__ void gemm_core(const bf16_t* A, const bf16_t* B,
                                          void* Cp, int K, int lda, int ldb,
                                          int ldc, int tm, int tn) {
    constexpr int BK = 32;
    constexpr int WM = BM / 2, WN = BN / 2;
    constexpr int FM = WM / 16, FN = WN / 16;
    __shared__ bf16_t As[BM * BK];
    __shared__ bf16_t Bs[BN * BK];
    const int tid = threadIdx.x;
    const int lane = tid & 63;
    const int wr = (tid >> 7) & 1;
    const int wc = (tid >> 6) & 1;

    A += (size_t)tm * lda;
    B += (size_t)tn * ldb;

    floatx4 acc[FM][FN] = {};

    for (int k0 = 0; k0 < K; k0 += BK) {
#pragma unroll
        for (int i = 0; i < (BM * 4) / 256; ++i) {
            int c = i * 256 + tid;
            int m = c >> 2, kc = c & 3;
            gld_lds16(A + (size_t)m * lda + k0 + kc * 8, As + c * 8);
        }
#pragma unroll
        for (int i = 0; i < (BN * 4) / 256; ++i) {
            int c = i * 256 + tid;
            int m = c >> 2, kc = c & 3;
            gld_lds16(B + (size_t)m * ldb + k0 + kc * 8, Bs + c * 8);
        }
        __syncthreads();

        bf16x8 aF[FM], bF[FN];
#pragma unroll
        for (int fm = 0; fm < FM; ++fm)
            aF[fm] = *(const bf16x8*)(As + (wr * WM + fm * 16 + (lane & 15)) * BK +
                                      (lane >> 4) * 8);
#pragma unroll
        for (int fn = 0; fn < FN; ++fn)
            bF[fn] = *(const bf16x8*)(Bs + (wc * WN + fn * 16 + (lane & 15)) * BK +
                                      (lane >> 4) * 8);
#pragma unroll
        for (int fm = 0; fm < FM; ++fm)
#pragma unroll
            for (int fn = 0; fn < FN; ++fn)
                acc[fm][fn] = __builtin_amdgcn_mfma_f32_16x16x32_bf16(
                    aF[fm], bF[fn], acc[fm][fn], 0, 0, 0);
        __syncthreads();
    }

    const int cr4 = (lane >> 4) * 4;
    const int cn = lane & 15;
#pragma unroll
    for (int fm = 0; fm < FM; ++fm)
#pragma unroll
        for (int fn = 0; fn < FN; ++fn)
#pragma unroll
            for (int r = 0; r < 4; ++r) {
                int m = tm + wr * WM + fm * 16 + cr4 + r;
                int n = tn + wc * WN + fn * 16 + cn;
                size_t idx = TRANS_OUT ? ((size_t)n * ldc + m)
                                       : ((size_t)m * ldc + n);
                if (OUT_MODE == 0)
                    ((float*)Cp)[idx] = acc[fm][fn][r];
                else if (OUT_MODE == 1)
                    ((unsigned short*)Cp)[idx] = f2bf(acc[fm][fn][r]);
                else
                    atomicAdd(&((float*)Cp)[idx], acc[fm][fn][r]);
            }
}

// ---- gram: G32[b] += xT[b] slice @ xT[b] slice^T, split-K over L ----
__global__ __launch_bounds__(256) void k_gram(const bf16_t* xT, float* G32) {
    int z = blockIdx.z, b = z / NS, s = z % NS;
    const bf16_t* Ab = xT + (size_t)b * DIN * LDIM + s * (LDIM / NS);
    gemm_core<128, 128, false, 2>(Ab, Ab, G32 + (size_t)b * DIN * DIN,
                                  LDIM / NS, LDIM, LDIM, DIN,
                                  blockIdx.x * 128, blockIdx.y * 128);
}

__global__ __launch_bounds__(256) void k_gconv(const float* G32, unsigned short* G16) {
    int g = blockIdx.x * 256 + threadIdx.x;
    float4 v = *(const float4*)(G32 + (size_t)g * 4);
    *(ushort4*)(G16 + (size_t)g * 4) =
        make_ushort4(f2bf(v.x), f2bf(v.y), f2bf(v.z), f2bf(v.w));
}

// ---- U_all[b] = G[b] @ Wv_cat, stored transposed UT[b][h*64+v][i] ----
__global__ __launch_bounds__(256) void k_proj(const bf16_t* G16, const bf16_t* WvT,
                                              unsigned short* UT) {
    int b = blockIdx.z;
    gemm_core<64, 64, true, 1>(G16 + (size_t)b * DIN * DIN, WvT,
                               UT + (size_t)b * DIN * DIN, DIN, DIN, DIN, DIN,
                               blockIdx.x * 64, blockIdx.y * 64);
}

// ---- M[b,h] = Wk[h]^T @ U[b,h], natural [dk][v] ----
__global__ __launch_bounds__(256) void k_kv(const bf16_t* WkT, const bf16_t* UT,
                                            unsigned short* M) {
    int z = blockIdx.z, b = z >> 3, h = z & 7;
    gemm_core<64, 64, false, 1>(WkT + (size_t)h * DK * DIN,
                                UT + (size_t)b * DIN * DIN + (size_t)h * DV * DIN,
                                M + (size_t)z * DK * DV, DIN, DIN, DIN, DV, 0, 0);
}

// ---- NT[b][o][h*64+dk] = (M[b,h] @ Wo[h])[dk][o] : A=WoT[h], B=M[b,h] ----
__global__ __launch_bounds__(256) void k_nw(const bf16_t* WoT, const bf16_t* M,
                                            unsigned short* NT) {
    int z = blockIdx.z, b = z >> 3, h = z & 7;
    gemm_core<64, 64, false, 1>(WoT + (size_t)h * DOUT * DV,
                                M + (size_t)z * DK * DV,
                                NT + (size_t)b * DOUT * DIN + h * DK, DV, DV,
                                DV, DIN, blockIdx.x * 64, 0);
}

// ---- CT[b][o][i] = (Wq_cat @ N_stack[b])^T : A=Wq_cat, B=NT[b] ----
__global__ __launch_bounds__(256) void k_cw(const bf16_t* Wq_cat, const bf16_t* NT,
                                            unsigned short* CT) {
    int b = blockIdx.z;
    gemm_core<64, 64, true, 1>(Wq_cat, NT + (size_t)b * DOUT * DIN,
                               CT + (size_t)b * DIN * DOUT, DIN, DIN, DIN, DIN,
                               blockIdx.x * 64, blockIdx.y * 64);
}

// ---- out[b] = x16[b] @ C[b] : A=x16, B=CT[b], fp32 out ----
__global__ __launch_bounds__(256) void k_out(const bf16_t* x16, const bf16_t* CT,
                                             float* out) {
    int b = blockIdx.z;
    gemm_core<128, 128, false, 0>(x16 + (size_t)b * LDIM * DIN,
                                  CT + (size_t)b * DIN * DOUT,
                                  out + (size_t)b * LDIM * DOUT, DIN, DIN, DIN,
                                  DOUT, blockIdx.x * 128, blockIdx.y * 128);
}

// ---------------- prep kernels ----------------
__global__ __launch_bounds__(256) void k_convx(const float* x, unsigned short* xb,
                                               unsigned short* xT) {
    __shared__ unsigned short T[64][65];
    int b = blockIdx.z, l0 = blockIdx.y * 64, d0 = blockIdx.x * 64;
    int tr = threadIdx.x >> 4, tc4 = (threadIdx.x & 15) * 4;
    const float* xp = x + (size_t)b * LDIM * DIN;
    unsigned short* xbp = xb + (size_t)b * LDIM * DIN;
#pragma unroll
    for (int p = 0; p < 4; ++p) {
        int l = p * 16 + tr;
        float4 v = *(const float4*)(xp + (size_t)(l0 + l) * DIN + d0 + tc4);
        unsigned short q0 = f2bf(v.x), q1 = f2bf(v.y), q2 = f2bf(v.z), q3 = f2bf(v.w);
        *(ushort4*)(xbp + (size_t)(l0 + l) * DIN + d0 + tc4) =
            make_ushort4(q0, q1, q2, q3);
        T[l][tc4 + 0] = q0; T[l][tc4 + 1] = q1;
        T[l][tc4 + 2] = q2; T[l][tc4 + 3] = q3;
    }
    __syncthreads();
    unsigned short* xTp = xT + (size_t)b * DIN * LDIM;
#pragma unroll
    for (int p = 0; p < 4; ++p) {
        int d = p * 16 + tr;
        ushort4 u = make_ushort4(T[tc4 + 0][d], T[tc4 + 1][d], T[tc4 + 2][d],
                                 T[tc4 + 3][d]);
        *(ushort4*)(xTp + (size_t)(d0 + d) * LDIM + l0 + tc4) = u;
    }
}

__global__ __launch_bounds__(256) void k_tconv(const float* src, unsigned short* dst,
                                               int rows, int cols) {
    __shared__ unsigned short T[64][65];
    int bt = blockIdx.z, r0 = blockIdx.y * 64, c0 = blockIdx.x * 64;
    src += (size_t)bt * rows * cols;
    dst += (size_t)bt * rows * cols;
    int tr = threadIdx.x >> 4, tc4 = (threadIdx.x & 15) * 4;
#pragma unroll
    for (int p = 0; p < 4; ++p) {
        int r = p * 16 + tr;
        float4 v = *(const float4*)(src + (size_t)(r0 + r) * cols + c0 + tc4);
        T[r][tc4 + 0] = f2bf(v.x); T[r][tc4 + 1] = f2bf(v.y);
        T[r][tc4 + 2] = f2bf(v.z); T[r][tc4 + 3] = f2bf(v.w);
    }
    __syncthreads();
#pragma unroll
    for (int p = 0; p < 4; ++p) {
        int c = p * 16 + tr;
        ushort4 u = make_ushort4(T[tc4 + 0][c], T[tc4 + 1][c], T[tc4 + 2][c],
                                 T[tc4 + 3][c]);
        *(ushort4*)(dst + (size_t)(c0 + c) * rows + r0 + tc4) = u;
    }
}

// Wq [h][i][dk] fp32 -> Wq_cat [i][h*64+dk] bf16
__global__ __launch_bounds__(256) void k_packq(const float* Wq, unsigned short* Wq_cat) {
    int g = blockIdx.x * 256 + threadIdx.x;
    int d4 = g * 4;
    int i = d4 >> 9, r = d4 & 511, h = r >> 6, dk = r & 63;
    float4 v = *(const float4*)(Wq + ((size_t)(h * DIN + i) * DK + dk));
    *(ushort4*)(Wq_cat + (size_t)d4) =
        make_ushort4(f2bf(v.x), f2bf(v.y), f2bf(v.z), f2bf(v.w));
}

extern "C" void kernel_launch(void* const* d_in, const int* in_sizes, int n_in,
                              void* d_out, int out_size, void* d_ws, size_t ws_size,
                              hipStream_t stream) {
    const float* x  = (const float*)d_in[0];
    const float* Wq = (const float*)d_in[1];
    const float* Wk = (const float*)d_in[2];
    const float* Wv = (const float*)d_in[3];
    const float* Wo = (const float*)d_in[4];
    float* out = (float*)d_out;

    unsigned short* w = (unsigned short*)d_ws;
    unsigned short* xb16  = w; w += (size_t)BDIM * LDIM * DIN;
    unsigned short* xT16  = w; w += (size_t)BDIM * DIN * LDIM;
    unsigned short* WqC   = w; w += (size_t)DIN * HDIM * DK;
    unsigned short* WkT   = w; w += (size_t)HDIM * DK * DIN;
    unsigned short* WvT   = w; w += (size_t)HDIM * DV * DIN;
    unsigned short* WoT   = w; w += (size_t)HDIM * DOUT * DV;
    unsigned short* G16   = w; w += (size_t)BDIM * DIN * DIN;
    unsigned short* UT    = w; w += (size_t)BDIM * DIN * DIN;
    unsigned short* Mbuf  = w; w += (size_t)BDIM * HDIM * DK * DV;
    unsigned short* NT    = w; w += (size_t)BDIM * DOUT * DIN;
    unsigned short* CT    = w; w += (size_t)BDIM * DIN * DOUT;
    float* G32 = (float*)w;  // BDIM*DIN*DIN floats

    hipMemsetAsync(G32, 0, (size_t)BDIM * DIN * DIN * sizeof(float), stream);

    k_convx<<<dim3(DIN / 64, LDIM / 64, BDIM), 256, 0, stream>>>(x, xb16, xT16);
    k_packq<<<dim3((DIN * HDIM * DK) / 1024), 256, 0, stream>>>(Wq, WqC);
    k_tconv<<<dim3(1, 8, HDIM), 256, 0, stream>>>(Wk, WkT, DIN, DK);
    k_tconv<<<dim3(1, 8, HDIM), 256, 0, stream>>>(Wv, WvT, DIN, DV);
    k_tconv<<<dim3(8, 1, HDIM), 256, 0, stream>>>(Wo, WoT, DV, DOUT);

    k_gram<<<dim3(4, 4, BDIM * NS), 256, 0, stream>>>((const bf16_t*)xT16, G32);
    k_gconv<<<dim3((BDIM * DIN * DIN) / 1024), 256, 0, stream>>>(G32, G16);
    k_proj<<<dim3(8, 8, BDIM), 256, 0, stream>>>((const bf16_t*)G16,
                                                 (const bf16_t*)WvT, UT);
    k_kv<<<dim3(1, 1, BDIM * HDIM), 256, 0, stream>>>((const bf16_t*)WkT,
                                                      (const bf16_t*)UT, Mbuf);
    k_nw<<<dim3(8, 1, BDIM * HDIM), 256, 0, stream>>>((const bf16_t*)WoT,
                                                      (const bf16_t*)Mbuf, NT);
    k_cw<<<dim3(8, 8, BDIM), 256, 0, stream>>>((const bf16_t*)WqC,
                                               (const bf16_t*)NT, CT);
    k_out<<<dim3(LDIM / 128, DOUT / 128, BDIM), 256, 0, stream>>>(
        (const bf16_t*)xb16, (const bf16_t*)CT, out);
}

// Round 4
// 142.215 us; speedup vs baseline: 2.2553x; 1.1430x over previous
//
#include <hip/hip_runtime.h>
#include <cstdint>

// out[b] = x[b] @ C[b],  C[b] = sum_h Wq[h] (Wk[h]^T G[b] Wv[h]) Wo[h],
// G[b] = x[b]^T x[b].  bf16 MFMA 16x16x32, fp32 accum.
// R4: 8 kernels (was 13). Gram split-K writes fp32 partials (no atomics, no
// memset) reduced by k_gred; weight prep merged into one kernel; kv+nw fused
// with M held in LDS.

#define BDIM 2
#define LDIM 4096
#define DIN 512
#define HDIM 8
#define DK 64
#define DV 64
#define DOUT 512
#define NS 16  // split-K slices for gram

using bf16_t = __bf16;
typedef __bf16 bf16x8 __attribute__((ext_vector_type(8)));
typedef float floatx4 __attribute__((ext_vector_type(4)));

__device__ __forceinline__ unsigned short f2bf(float f) {
    unsigned int u = __builtin_bit_cast(unsigned int, f);
    u += 0x7FFFu + ((u >> 16) & 1u);
    return (unsigned short)(u >> 16);
}

__device__ __forceinline__ void gld_lds16(const void* g, void* l) {
    __builtin_amdgcn_global_load_lds(
        (const __attribute__((address_space(1))) void*)g,
        (__attribute__((address_space(3))) void*)l, 16, 0, 0);
}

// ---------------- generic TN MFMA GEMM core ----------------
// C[m][n] = sum_k A[m][k]*B[n][k]; A,B k-contiguous bf16. 256 thr, 2x2 waves.
// OUT_MODE: 0 = f32 store, 1 = bf16 store.
template <int BM, int BN, bool TRANS_OUT, int OUT_MODE>
__device__ __forceinline__ void gemm_core(const bf16_t* A, const bf16_t* B,
                                          void* Cp, int K, int lda, int ldb,
                                          int ldc, int tm, int tn) {
    constexpr int BK = 32;
    constexpr int WM = BM / 2, WN = BN / 2;
    constexpr int FM = WM / 16, FN = WN / 16;
    __shared__ bf16_t As[BM * BK];
    __shared__ bf16_t Bs[BN * BK];
    const int tid = threadIdx.x;
    const int lane = tid & 63;
    const int wr = (tid >> 7) & 1;
    const int wc = (tid >> 6) & 1;

    A += (size_t)tm * lda;
    B += (size_t)tn * ldb;

    floatx4 acc[FM][FN] = {};

    for (int k0 = 0; k0 < K; k0 += BK) {
#pragma unroll
        for (int i = 0; i < (BM * 4) / 256; ++i) {
            int c = i * 256 + tid;
            int m = c >> 2, kc = c & 3;
            gld_lds16(A + (size_t)m * lda + k0 + kc * 8, As + c * 8);
        }
#pragma unroll
        for (int i = 0; i < (BN * 4) / 256; ++i) {
            int c = i * 256 + tid;
            int m = c >> 2, kc = c & 3;
            gld_lds16(B + (size_t)m * ldb + k0 + kc * 8, Bs + c * 8);
        }
        __syncthreads();

        bf16x8 aF[FM], bF[FN];
#pragma unroll
        for (int fm = 0; fm < FM; ++fm)
            aF[fm] = *(const bf16x8*)(As + (wr * WM + fm * 16 + (lane & 15)) * BK +
                                      (lane >> 4) * 8);
#pragma unroll
        for (int fn = 0; fn < FN; ++fn)
            bF[fn] = *(const bf16x8*)(Bs + (wc * WN + fn * 16 + (lane & 15)) * BK +
                                      (lane >> 4) * 8);
#pragma unroll
        for (int fm = 0; fm < FM; ++fm)
#pragma unroll
            for (int fn = 0; fn < FN; ++fn)
                acc[fm][fn] = __builtin_amdgcn_mfma_f32_16x16x32_bf16(
                    aF[fm], bF[fn], acc[fm][fn], 0, 0, 0);
        __syncthreads();
    }

    const int cr4 = (lane >> 4) * 4;
    const int cn = lane & 15;
#pragma unroll
    for (int fm = 0; fm < FM; ++fm)
#pragma unroll
        for (int fn = 0; fn < FN; ++fn)
#pragma unroll
            for (int r = 0; r < 4; ++r) {
                int m = tm + wr * WM + fm * 16 + cr4 + r;
                int n = tn + wc * WN + fn * 16 + cn;
                size_t idx = TRANS_OUT ? ((size_t)n * ldc + m)
                                       : ((size_t)m * ldc + n);
                if (OUT_MODE == 0)
                    ((float*)Cp)[idx] = acc[fm][fn][r];
                else
                    ((unsigned short*)Cp)[idx] = f2bf(acc[fm][fn][r]);
            }
}

// ---- gram: Gp[b,s] = xT[b] slice @ slice^T (fp32 partial, no atomics) ----
__global__ __launch_bounds__(256) void k_gram(const bf16_t* xT, float* Gp) {
    int z = blockIdx.z, b = z / NS, s = z % NS;
    const bf16_t* Ab = xT + (size_t)b * DIN * LDIM + s * (LDIM / NS);
    gemm_core<128, 128, false, 0>(Ab, Ab, Gp + (size_t)z * DIN * DIN,
                                  LDIM / NS, LDIM, LDIM, DIN,
                                  blockIdx.x * 128, blockIdx.y * 128);
}

// ---- reduce NS partials -> bf16 G ----
__global__ __launch_bounds__(256) void k_gred(const float* Gp, unsigned short* G16) {
    size_t idx = ((size_t)blockIdx.x * 256 + threadIdx.x) * 4;
    int b = (int)(idx >> 18);
    size_t r = idx & (((size_t)1 << 18) - 1);
    float4 s = make_float4(0.f, 0.f, 0.f, 0.f);
#pragma unroll
    for (int sl = 0; sl < NS; ++sl) {
        float4 v = *(const float4*)(Gp + (((size_t)(b * NS + sl)) << 18) + r);
        s.x += v.x; s.y += v.y; s.z += v.z; s.w += v.w;
    }
    *(ushort4*)(G16 + idx) =
        make_ushort4(f2bf(s.x), f2bf(s.y), f2bf(s.z), f2bf(s.w));
}

// ---- U_all[b] = G[b] @ Wv_cat, stored transposed UT[b][h*64+v][i] ----
__global__ __launch_bounds__(256) void k_proj(const bf16_t* G16, const bf16_t* WvT,
                                              unsigned short* UT) {
    int b = blockIdx.z;
    gemm_core<64, 64, true, 1>(G16 + (size_t)b * DIN * DIN, WvT,
                               UT + (size_t)b * DIN * DIN, DIN, DIN, DIN, DIN,
                               blockIdx.x * 64, blockIdx.y * 64);
}

// ---- fused kv+nw: M = WkT[h] @ U[b,h] (LDS), NT[b][o][h*64+dk] = (M@Wo)[dk][o]
__global__ __launch_bounds__(256) void k_kvnw(const bf16_t* WkT, const bf16_t* UT,
                                              const bf16_t* WoT, unsigned short* NT) {
    int b = blockIdx.x >> 3, h = blockIdx.x & 7;
    __shared__ bf16_t As[64 * 32];
    __shared__ bf16_t Bs[64 * 32];
    __shared__ bf16_t Ms[64 * 64];
    __shared__ bf16_t Aw[64 * 64];
    const int tid = threadIdx.x;
    const int lane = tid & 63;
    const int wr = (tid >> 7) & 1, wc = (tid >> 6) & 1;
    const int cr4 = (lane >> 4) * 4, cn = lane & 15;

    // stage 1: M[dk][v] = sum_i WkT[h][dk][i] * UT[b][h*64+v][i]
    const bf16_t* A = WkT + (size_t)h * DK * DIN;
    const bf16_t* B = UT + (size_t)b * DIN * DIN + (size_t)h * DV * DIN;
    floatx4 acc[2][2] = {};
    for (int k0 = 0; k0 < DIN; k0 += 32) {
        int c = tid, m = c >> 2, kc = c & 3;
        gld_lds16(A + (size_t)m * DIN + k0 + kc * 8, As + c * 8);
        gld_lds16(B + (size_t)m * DIN + k0 + kc * 8, Bs + c * 8);
        __syncthreads();
        bf16x8 aF[2], bF[2];
#pragma unroll
        for (int f = 0; f < 2; ++f) {
            aF[f] = *(const bf16x8*)(As + (wr * 32 + f * 16 + cn) * 32 + (lane >> 4) * 8);
            bF[f] = *(const bf16x8*)(Bs + (wc * 32 + f * 16 + cn) * 32 + (lane >> 4) * 8);
        }
#pragma unroll
        for (int fm = 0; fm < 2; ++fm)
#pragma unroll
            for (int fn = 0; fn < 2; ++fn)
                acc[fm][fn] = __builtin_amdgcn_mfma_f32_16x16x32_bf16(
                    aF[fm], bF[fn], acc[fm][fn], 0, 0, 0);
        __syncthreads();
    }
#pragma unroll
    for (int fm = 0; fm < 2; ++fm)
#pragma unroll
        for (int fn = 0; fn < 2; ++fn)
#pragma unroll
            for (int r = 0; r < 4; ++r) {
                int m = wr * 32 + fm * 16 + cr4 + r;
                int n = wc * 32 + fn * 16 + cn;
                ((unsigned short*)Ms)[m * 64 + n] = f2bf(acc[fm][fn][r]);
            }
    __syncthreads();

    // stage 2: NT rows o, cols h*64+dk: out[o][dk] = sum_v WoT[h][o][v]*M[dk][v]
    const bf16_t* Ao = WoT + (size_t)h * DOUT * DV;
    unsigned short* NTb = NT + (size_t)b * DOUT * DIN + h * DK;
    for (int mo = 0; mo < 8; ++mo) {
        floatx4 a2[2][2] = {};
#pragma unroll
        for (int i = 0; i < 2; ++i) {
            int c = i * 256 + tid, m = c >> 3, kc = c & 7;
            gld_lds16(Ao + (size_t)(mo * 64 + m) * DV + kc * 8, Aw + c * 8);
        }
        __syncthreads();
#pragma unroll
        for (int k0 = 0; k0 < 64; k0 += 32) {
            bf16x8 aF[2], bF[2];
#pragma unroll
            for (int f = 0; f < 2; ++f) {
                aF[f] = *(const bf16x8*)(Aw + (wr * 32 + f * 16 + cn) * 64 + k0 + (lane >> 4) * 8);
                bF[f] = *(const bf16x8*)(Ms + (wc * 32 + f * 16 + cn) * 64 + k0 + (lane >> 4) * 8);
            }
#pragma unroll
            for (int fm = 0; fm < 2; ++fm)
#pragma unroll
                for (int fn = 0; fn < 2; ++fn)
                    a2[fm][fn] = __builtin_amdgcn_mfma_f32_16x16x32_bf16(
                        aF[fm], bF[fn], a2[fm][fn], 0, 0, 0);
        }
#pragma unroll
        for (int fm = 0; fm < 2; ++fm)
#pragma unroll
            for (int fn = 0; fn < 2; ++fn)
#pragma unroll
                for (int r = 0; r < 4; ++r) {
                    int m = wr * 32 + fm * 16 + cr4 + r;
                    int n = wc * 32 + fn * 16 + cn;
                    NTb[(size_t)(mo * 64 + m) * DIN + n] = f2bf(a2[fm][fn][r]);
                }
        __syncthreads();
    }
}

// ---- CT[b][o][i] = (Wq_cat @ N_stack[b])^T ----
__global__ __launch_bounds__(256) void k_cw(const bf16_t* Wq_cat, const bf16_t* NT,
                                            unsigned short* CT) {
    int b = blockIdx.z;
    gemm_core<64, 64, true, 1>(Wq_cat, NT + (size_t)b * DOUT * DIN,
                               CT + (size_t)b * DIN * DOUT, DIN, DIN, DIN, DIN,
                               blockIdx.x * 64, blockIdx.y * 64);
}

// ---- out[b] = x16[b] @ C[b], fp32 out ----
__global__ __launch_bounds__(256) void k_out(const bf16_t* x16, const bf16_t* CT,
                                             float* out) {
    int b = blockIdx.z;
    gemm_core<128, 128, false, 0>(x16 + (size_t)b * LDIM * DIN,
                                  CT + (size_t)b * DIN * DOUT,
                                  out + (size_t)b * LDIM * DOUT, DIN, DIN, DIN,
                                  DOUT, blockIdx.x * 128, blockIdx.y * 128);
}

// ---------------- prep kernels ----------------
__global__ __launch_bounds__(256) void k_convx(const float* x, unsigned short* xb,
                                               unsigned short* xT) {
    __shared__ unsigned short T[64][65];
    int b = blockIdx.z, l0 = blockIdx.y * 64, d0 = blockIdx.x * 64;
    int tr = threadIdx.x >> 4, tc4 = (threadIdx.x & 15) * 4;
    const float* xp = x + (size_t)b * LDIM * DIN;
    unsigned short* xbp = xb + (size_t)b * LDIM * DIN;
#pragma unroll
    for (int p = 0; p < 4; ++p) {
        int l = p * 16 + tr;
        float4 v = *(const float4*)(xp + (size_t)(l0 + l) * DIN + d0 + tc4);
        unsigned short q0 = f2bf(v.x), q1 = f2bf(v.y), q2 = f2bf(v.z), q3 = f2bf(v.w);
        *(ushort4*)(xbp + (size_t)(l0 + l) * DIN + d0 + tc4) =
            make_ushort4(q0, q1, q2, q3);
        T[l][tc4 + 0] = q0; T[l][tc4 + 1] = q1;
        T[l][tc4 + 2] = q2; T[l][tc4 + 3] = q3;
    }
    __syncthreads();
    unsigned short* xTp = xT + (size_t)b * DIN * LDIM;
#pragma unroll
    for (int p = 0; p < 4; ++p) {
        int d = p * 16 + tr;
        ushort4 u = make_ushort4(T[tc4 + 0][d], T[tc4 + 1][d], T[tc4 + 2][d],
                                 T[tc4 + 3][d]);
        *(ushort4*)(xTp + (size_t)(d0 + d) * LDIM + l0 + tc4) = u;
    }
}

// merged weight prep: job0 = Wq pack, job1 = Wk^T, job2 = Wv^T, job3 = Wo^T
__global__ __launch_bounds__(256) void k_prep(const float* Wq, const float* Wk,
                                              const float* Wv, const float* Wo,
                                              unsigned short* WqC, unsigned short* WkT,
                                              unsigned short* WvT, unsigned short* WoT) {
    __shared__ unsigned short T[64][65];
    int t = blockIdx.x, job = blockIdx.y, h = blockIdx.z;
    int tr = threadIdx.x >> 4, tc4 = (threadIdx.x & 15) * 4;
    if (job == 0) {
        const float* src = Wq + (size_t)h * DIN * DK;
#pragma unroll
        for (int p = 0; p < 4; ++p) {
            int i = t * 64 + p * 16 + tr;
            float4 v = *(const float4*)(src + (size_t)i * DK + tc4);
            *(ushort4*)(WqC + (size_t)i * (HDIM * DK) + h * DK + tc4) =
                make_ushort4(f2bf(v.x), f2bf(v.y), f2bf(v.z), f2bf(v.w));
        }
        return;
    }
    const float* src;
    unsigned short* dst;
    int rows, cols, r0, c0;
    if (job == 1) {
        src = Wk + (size_t)h * DIN * DK; dst = WkT + (size_t)h * DK * DIN;
        rows = DIN; cols = DK; r0 = t * 64; c0 = 0;
    } else if (job == 2) {
        src = Wv + (size_t)h * DIN * DV; dst = WvT + (size_t)h * DV * DIN;
        rows = DIN; cols = DV; r0 = t * 64; c0 = 0;
    } else {
        src = Wo + (size_t)h * DV * DOUT; dst = WoT + (size_t)h * DOUT * DV;
        rows = DV; cols = DOUT; r0 = 0; c0 = t * 64;
    }
#pragma unroll
    for (int p = 0; p < 4; ++p) {
        int r = p * 16 + tr;
        float4 v = *(const float4*)(src + (size_t)(r0 + r) * cols + c0 + tc4);
        T[r][tc4 + 0] = f2bf(v.x); T[r][tc4 + 1] = f2bf(v.y);
        T[r][tc4 + 2] = f2bf(v.z); T[r][tc4 + 3] = f2bf(v.w);
    }
    __syncthreads();
#pragma unroll
    for (int p = 0; p < 4; ++p) {
        int c = p * 16 + tr;
        ushort4 u = make_ushort4(T[tc4 + 0][c], T[tc4 + 1][c], T[tc4 + 2][c],
                                 T[tc4 + 3][c]);
        *(ushort4*)(dst + (size_t)(c0 + c) * rows + r0 + tc4) = u;
    }
}

extern "C" void kernel_launch(void* const* d_in, const int* in_sizes, int n_in,
                              void* d_out, int out_size, void* d_ws, size_t ws_size,
                              hipStream_t stream) {
    const float* x  = (const float*)d_in[0];
    const float* Wq = (const float*)d_in[1];
    const float* Wk = (const float*)d_in[2];
    const float* Wv = (const float*)d_in[3];
    const float* Wo = (const float*)d_in[4];
    float* out = (float*)d_out;

    unsigned short* w = (unsigned short*)d_ws;
    unsigned short* xb16  = w; w += (size_t)BDIM * LDIM * DIN;
    unsigned short* xT16  = w; w += (size_t)BDIM * DIN * LDIM;
    unsigned short* WqC   = w; w += (size_t)DIN * HDIM * DK;
    unsigned short* WkT   = w; w += (size_t)HDIM * DK * DIN;
    unsigned short* WvT   = w; w += (size_t)HDIM * DV * DIN;
    unsigned short* WoT   = w; w += (size_t)HDIM * DOUT * DV;
    unsigned short* G16   = w; w += (size_t)BDIM * DIN * DIN;
    unsigned short* UT    = w; w += (size_t)BDIM * DIN * DIN;
    unsigned short* NT    = w; w += (size_t)BDIM * DOUT * DIN;
    unsigned short* CT    = w; w += (size_t)BDIM * DIN * DOUT;
    float* Gp = (float*)(((uintptr_t)w + 255) & ~(uintptr_t)255);  // BDIM*NS*512*512 f32

    k_prep<<<dim3(8, 4, HDIM), 256, 0, stream>>>(Wq, Wk, Wv, Wo, WqC, WkT, WvT, WoT);
    k_convx<<<dim3(DIN / 64, LDIM / 64, BDIM), 256, 0, stream>>>(x, xb16, xT16);

    k_gram<<<dim3(4, 4, BDIM * NS), 256, 0, stream>>>((const bf16_t*)xT16, Gp);
    k_gred<<<dim3((BDIM * DIN * DIN) / 1024), 256, 0, stream>>>(Gp, G16);
    k_proj<<<dim3(8, 8, BDIM), 256, 0, stream>>>((const bf16_t*)G16,
                                                 (const bf16_t*)WvT, UT);
    k_kvnw<<<dim3(BDIM * HDIM), 256, 0, stream>>>((const bf16_t*)WkT,
                                                  (const bf16_t*)UT,
                                                  (const bf16_t*)WoT, NT);
    k_cw<<<dim3(8, 8, BDIM), 256, 0, stream>>>((const bf16_t*)WqC,
                                               (const bf16_t*)NT, CT);
    k_out<<<dim3(LDIM / 128, DOUT / 128, BDIM), 256, 0, stream>>>(
        (const bf16_t*)xb16, (const bf16_t*)CT, out);
}

// Round 5
// 133.467 us; speedup vs baseline: 2.4031x; 1.0655x over previous
//
#include <hip/hip_runtime.h>
#include <cstdint>

// out[b] = x[b] @ C[b],  C[b] = sum_h Wq[h] (Wk[h]^T G[b] Wv[h]) Wo[h],
// G[b] = x[b]^T x[b].  bf16 MFMA 16x16x32, fp32 accum.
// R5: 7 kernels. NS=8 split-K gram; BK=64 for the two big GEMMs; k_kvnw
// parallelized to 128 blocks (recompute M per slab); prep+convx merged.

#define BDIM 2
#define LDIM 4096
#define DIN 512
#define HDIM 8
#define DK 64
#define DV 64
#define DOUT 512
#define NS 8  // split-K slices for gram

using bf16_t = __bf16;
typedef __bf16 bf16x8 __attribute__((ext_vector_type(8)));
typedef float floatx4 __attribute__((ext_vector_type(4)));

__device__ __forceinline__ unsigned short f2bf(float f) {
    unsigned int u = __builtin_bit_cast(unsigned int, f);
    u += 0x7FFFu + ((u >> 16) & 1u);
    return (unsigned short)(u >> 16);
}

__device__ __forceinline__ void gld_lds16(const void* g, void* l) {
    __builtin_amdgcn_global_load_lds(
        (const __attribute__((address_space(1))) void*)g,
        (__attribute__((address_space(3))) void*)l, 16, 0, 0);
}

// ---------------- generic TN MFMA GEMM core ----------------
// C[m][n] = sum_k A[m][k]*B[n][k]; A,B k-contiguous bf16. 256 thr, 2x2 waves.
// OUT_MODE: 0 = f32 store, 1 = bf16 store.
template <int BM, int BN, int BK, bool TRANS_OUT, int OUT_MODE>
__device__ __forceinline__ void gemm_core(const bf16_t* A, const bf16_t* B,
                                          void* Cp, int K, int lda, int ldb,
                                          int ldc, int tm, int tn) {
    constexpr int WM = BM / 2, WN = BN / 2;
    constexpr int FM = WM / 16, FN = WN / 16;
    constexpr int CPR = BK / 8;  // 16B chunks per row
    __shared__ bf16_t As[BM * BK];
    __shared__ bf16_t Bs[BN * BK];
    const int tid = threadIdx.x;
    const int lane = tid & 63;
    const int wr = (tid >> 7) & 1;
    const int wc = (tid >> 6) & 1;

    A += (size_t)tm * lda;
    B += (size_t)tn * ldb;

    floatx4 acc[FM][FN] = {};

    for (int k0 = 0; k0 < K; k0 += BK) {
#pragma unroll
        for (int i = 0; i < (BM * CPR) / 256; ++i) {
            int c = i * 256 + tid;
            int m = c / CPR, kc = c % CPR;
            gld_lds16(A + (size_t)m * lda + k0 + kc * 8, As + c * 8);
        }
#pragma unroll
        for (int i = 0; i < (BN * CPR) / 256; ++i) {
            int c = i * 256 + tid;
            int m = c / CPR, kc = c % CPR;
            gld_lds16(B + (size_t)m * ldb + k0 + kc * 8, Bs + c * 8);
        }
        __syncthreads();

#pragma unroll
        for (int kk = 0; kk < BK; kk += 32) {
            bf16x8 aF[FM], bF[FN];
#pragma unroll
            for (int fm = 0; fm < FM; ++fm)
                aF[fm] = *(const bf16x8*)(As + (wr * WM + fm * 16 + (lane & 15)) * BK +
                                          kk + (lane >> 4) * 8);
#pragma unroll
            for (int fn = 0; fn < FN; ++fn)
                bF[fn] = *(const bf16x8*)(Bs + (wc * WN + fn * 16 + (lane & 15)) * BK +
                                          kk + (lane >> 4) * 8);
#pragma unroll
            for (int fm = 0; fm < FM; ++fm)
#pragma unroll
                for (int fn = 0; fn < FN; ++fn)
                    acc[fm][fn] = __builtin_amdgcn_mfma_f32_16x16x32_bf16(
                        aF[fm], bF[fn], acc[fm][fn], 0, 0, 0);
        }
        __syncthreads();
    }

    const int cr4 = (lane >> 4) * 4;
    const int cn = lane & 15;
#pragma unroll
    for (int fm = 0; fm < FM; ++fm)
#pragma unroll
        for (int fn = 0; fn < FN; ++fn)
#pragma unroll
            for (int r = 0; r < 4; ++r) {
                int m = tm + wr * WM + fm * 16 + cr4 + r;
                int n = tn + wc * WN + fn * 16 + cn;
                size_t idx = TRANS_OUT ? ((size_t)n * ldc + m)
                                       : ((size_t)m * ldc + n);
                if (OUT_MODE == 0)
                    ((float*)Cp)[idx] = acc[fm][fn][r];
                else
                    ((unsigned short*)Cp)[idx] = f2bf(acc[fm][fn][r]);
            }
}

// ---- gram: Gp[b,s] = xT[b] slice @ slice^T (fp32 partial) ----
__global__ __launch_bounds__(256) void k_gram(const bf16_t* xT, float* Gp) {
    int z = blockIdx.z, b = z / NS, s = z % NS;
    const bf16_t* Ab = xT + (size_t)b * DIN * LDIM + s * (LDIM / NS);
    gemm_core<128, 128, 64, false, 0>(Ab, Ab, Gp + (size_t)z * DIN * DIN,
                                      LDIM / NS, LDIM, LDIM, DIN,
                                      blockIdx.x * 128, blockIdx.y * 128);
}

// ---- reduce NS partials -> bf16 G ----
__global__ __launch_bounds__(256) void k_gred(const float* Gp, unsigned short* G16) {
    size_t idx = ((size_t)blockIdx.x * 256 + threadIdx.x) * 4;
    int b = (int)(idx >> 18);
    size_t r = idx & (((size_t)1 << 18) - 1);
    float4 s = make_float4(0.f, 0.f, 0.f, 0.f);
#pragma unroll
    for (int sl = 0; sl < NS; ++sl) {
        float4 v = *(const float4*)(Gp + (((size_t)(b * NS + sl)) << 18) + r);
        s.x += v.x; s.y += v.y; s.z += v.z; s.w += v.w;
    }
    *(ushort4*)(G16 + idx) =
        make_ushort4(f2bf(s.x), f2bf(s.y), f2bf(s.z), f2bf(s.w));
}

// ---- U_all[b] = G[b] @ Wv_cat, stored transposed UT[b][h*64+v][i] ----
__global__ __launch_bounds__(256) void k_proj(const bf16_t* G16, const bf16_t* WvT,
                                              unsigned short* UT) {
    int b = blockIdx.z;
    gemm_core<64, 64, 32, true, 1>(G16 + (size_t)b * DIN * DIN, WvT,
                                   UT + (size_t)b * DIN * DIN, DIN, DIN, DIN,
                                   DIN, blockIdx.x * 64, blockIdx.y * 64);
}

// ---- fused kv+nw, one 64-row output slab per block (recompute M) ----
// M[dk][v] = sum_i WkT[h][dk][i]*UT[b][h*64+v][i];
// NT[b][mo*64+o][h*64+dk] = sum_v WoT[h][mo*64+o][v]*M[dk][v]
__global__ __launch_bounds__(256) void k_kvnw(const bf16_t* WkT, const bf16_t* UT,
                                              const bf16_t* WoT, unsigned short* NT) {
    int mo = blockIdx.x;
    int b = blockIdx.y >> 3, h = blockIdx.y & 7;
    __shared__ bf16_t As[64 * 32];
    __shared__ bf16_t Bs[64 * 32];
    __shared__ bf16_t Ms[64 * 64];
    __shared__ bf16_t Aw[64 * 64];
    const int tid = threadIdx.x;
    const int lane = tid & 63;
    const int wr = (tid >> 7) & 1, wc = (tid >> 6) & 1;
    const int cr4 = (lane >> 4) * 4, cn = lane & 15;

    // stage 1: M = WkT[h] @ U[b,h]
    const bf16_t* A = WkT + (size_t)h * DK * DIN;
    const bf16_t* B = UT + (size_t)b * DIN * DIN + (size_t)h * DV * DIN;
    floatx4 acc[2][2] = {};
    for (int k0 = 0; k0 < DIN; k0 += 32) {
        int c = tid, m = c >> 2, kc = c & 3;
        gld_lds16(A + (size_t)m * DIN + k0 + kc * 8, As + c * 8);
        gld_lds16(B + (size_t)m * DIN + k0 + kc * 8, Bs + c * 8);
        __syncthreads();
        bf16x8 aF[2], bF[2];
#pragma unroll
        for (int f = 0; f < 2; ++f) {
            aF[f] = *(const bf16x8*)(As + (wr * 32 + f * 16 + cn) * 32 + (lane >> 4) * 8);
            bF[f] = *(const bf16x8*)(Bs + (wc * 32 + f * 16 + cn) * 32 + (lane >> 4) * 8);
        }
#pragma unroll
        for (int fm = 0; fm < 2; ++fm)
#pragma unroll
            for (int fn = 0; fn < 2; ++fn)
                acc[fm][fn] = __builtin_amdgcn_mfma_f32_16x16x32_bf16(
                    aF[fm], bF[fn], acc[fm][fn], 0, 0, 0);
        __syncthreads();
    }
#pragma unroll
    for (int fm = 0; fm < 2; ++fm)
#pragma unroll
        for (int fn = 0; fn < 2; ++fn)
#pragma unroll
            for (int r = 0; r < 4; ++r) {
                int m = wr * 32 + fm * 16 + cr4 + r;
                int n = wc * 32 + fn * 16 + cn;
                ((unsigned short*)Ms)[m * 64 + n] = f2bf(acc[fm][fn][r]);
            }

    // stage 2: slab mo of WoT[h] against Ms
    const bf16_t* Ao = WoT + (size_t)h * DOUT * DV;
    unsigned short* NTb = NT + (size_t)b * DOUT * DIN + h * DK;
#pragma unroll
    for (int i = 0; i < 2; ++i) {
        int c = i * 256 + tid, m = c >> 3, kc = c & 7;
        gld_lds16(Ao + (size_t)(mo * 64 + m) * DV + kc * 8, Aw + c * 8);
    }
    __syncthreads();
    floatx4 a2[2][2] = {};
#pragma unroll
    for (int k0 = 0; k0 < 64; k0 += 32) {
        bf16x8 aF[2], bF[2];
#pragma unroll
        for (int f = 0; f < 2; ++f) {
            aF[f] = *(const bf16x8*)(Aw + (wr * 32 + f * 16 + cn) * 64 + k0 + (lane >> 4) * 8);
            bF[f] = *(const bf16x8*)(Ms + (wc * 32 + f * 16 + cn) * 64 + k0 + (lane >> 4) * 8);
        }
#pragma unroll
        for (int fm = 0; fm < 2; ++fm)
#pragma unroll
            for (int fn = 0; fn < 2; ++fn)
                a2[fm][fn] = __builtin_amdgcn_mfma_f32_16x16x32_bf16(
                    aF[fm], bF[fn], a2[fm][fn], 0, 0, 0);
    }
#pragma unroll
    for (int fm = 0; fm < 2; ++fm)
#pragma unroll
        for (int fn = 0; fn < 2; ++fn)
#pragma unroll
            for (int r = 0; r < 4; ++r) {
                int m = wr * 32 + fm * 16 + cr4 + r;
                int n = wc * 32 + fn * 16 + cn;
                NTb[(size_t)(mo * 64 + m) * DIN + n] = f2bf(a2[fm][fn][r]);
            }
}

// ---- CT[b][o][i] = (Wq_cat @ N_stack[b])^T ----
__global__ __launch_bounds__(256) void k_cw(const bf16_t* Wq_cat, const bf16_t* NT,
                                            unsigned short* CT) {
    int b = blockIdx.z;
    gemm_core<64, 64, 32, true, 1>(Wq_cat, NT + (size_t)b * DOUT * DIN,
                                   CT + (size_t)b * DIN * DOUT, DIN, DIN, DIN,
                                   DIN, blockIdx.x * 64, blockIdx.y * 64);
}

// ---- out[b] = x16[b] @ C[b], fp32 out ----
__global__ __launch_bounds__(256) void k_out(const bf16_t* x16, const bf16_t* CT,
                                             float* out) {
    int b = blockIdx.z;
    gemm_core<128, 128, 64, false, 0>(x16 + (size_t)b * LDIM * DIN,
                                      CT + (size_t)b * DIN * DOUT,
                                      out + (size_t)b * LDIM * DOUT, DIN, DIN,
                                      DIN, DOUT, blockIdx.x * 128,
                                      blockIdx.y * 128);
}

// ---------------- merged prep: x convert+transpose AND weight prep ----------------
// blocks [0,1024): convx; [1024,1280): weight jobs
__global__ __launch_bounds__(256) void k_prep2(
    const float* x, const float* Wq, const float* Wk, const float* Wv,
    const float* Wo, unsigned short* xb, unsigned short* xT,
    unsigned short* WqC, unsigned short* WkT, unsigned short* WvT,
    unsigned short* WoT) {
    __shared__ unsigned short T[64][65];
    int tr = threadIdx.x >> 4, tc4 = (threadIdx.x & 15) * 4;
    int bid = blockIdx.x;
    if (bid < 1024) {
        int b = bid >> 9, r = bid & 511;
        int d0 = (r & 7) * 64, l0 = (r >> 3) * 64;
        const float* xp = x + (size_t)b * LDIM * DIN;
        unsigned short* xbp = xb + (size_t)b * LDIM * DIN;
#pragma unroll
        for (int p = 0; p < 4; ++p) {
            int l = p * 16 + tr;
            float4 v = *(const float4*)(xp + (size_t)(l0 + l) * DIN + d0 + tc4);
            unsigned short q0 = f2bf(v.x), q1 = f2bf(v.y), q2 = f2bf(v.z),
                           q3 = f2bf(v.w);
            *(ushort4*)(xbp + (size_t)(l0 + l) * DIN + d0 + tc4) =
                make_ushort4(q0, q1, q2, q3);
            T[l][tc4 + 0] = q0; T[l][tc4 + 1] = q1;
            T[l][tc4 + 2] = q2; T[l][tc4 + 3] = q3;
        }
        __syncthreads();
        unsigned short* xTp = xT + (size_t)b * DIN * LDIM;
#pragma unroll
        for (int p = 0; p < 4; ++p) {
            int d = p * 16 + tr;
            ushort4 u = make_ushort4(T[tc4 + 0][d], T[tc4 + 1][d], T[tc4 + 2][d],
                                     T[tc4 + 3][d]);
            *(ushort4*)(xTp + (size_t)(d0 + d) * LDIM + l0 + tc4) = u;
        }
        return;
    }
    int p_ = bid - 1024;
    int t = p_ & 7, job = (p_ >> 3) & 3, h = p_ >> 5;
    if (job == 0) {
        const float* src = Wq + (size_t)h * DIN * DK;
#pragma unroll
        for (int p = 0; p < 4; ++p) {
            int i = t * 64 + p * 16 + tr;
            float4 v = *(const float4*)(src + (size_t)i * DK + tc4);
            *(ushort4*)(WqC + (size_t)i * (HDIM * DK) + h * DK + tc4) =
                make_ushort4(f2bf(v.x), f2bf(v.y), f2bf(v.z), f2bf(v.w));
        }
        return;
    }
    const float* src;
    unsigned short* dst;
    int rows, cols, r0, c0;
    if (job == 1) {
        src = Wk + (size_t)h * DIN * DK; dst = WkT + (size_t)h * DK * DIN;
        rows = DIN; cols = DK; r0 = t * 64; c0 = 0;
    } else if (job == 2) {
        src = Wv + (size_t)h * DIN * DV; dst = WvT + (size_t)h * DV * DIN;
        rows = DIN; cols = DV; r0 = t * 64; c0 = 0;
    } else {
        src = Wo + (size_t)h * DV * DOUT; dst = WoT + (size_t)h * DOUT * DV;
        rows = DV; cols = DOUT; r0 = 0; c0 = t * 64;
    }
#pragma unroll
    for (int p = 0; p < 4; ++p) {
        int r = p * 16 + tr;
        float4 v = *(const float4*)(src + (size_t)(r0 + r) * cols + c0 + tc4);
        T[r][tc4 + 0] = f2bf(v.x); T[r][tc4 + 1] = f2bf(v.y);
        T[r][tc4 + 2] = f2bf(v.z); T[r][tc4 + 3] = f2bf(v.w);
    }
    __syncthreads();
#pragma unroll
    for (int p = 0; p < 4; ++p) {
        int c = p * 16 + tr;
        ushort4 u = make_ushort4(T[tc4 + 0][c], T[tc4 + 1][c], T[tc4 + 2][c],
                                 T[tc4 + 3][c]);
        *(ushort4*)(dst + (size_t)(c0 + c) * rows + r0 + tc4) = u;
    }
}

extern "C" void kernel_launch(void* const* d_in, const int* in_sizes, int n_in,
                              void* d_out, int out_size, void* d_ws, size_t ws_size,
                              hipStream_t stream) {
    const float* x  = (const float*)d_in[0];
    const float* Wq = (const float*)d_in[1];
    const float* Wk = (const float*)d_in[2];
    const float* Wv = (const float*)d_in[3];
    const float* Wo = (const float*)d_in[4];
    float* out = (float*)d_out;

    unsigned short* w = (unsigned short*)d_ws;
    unsigned short* xb16  = w; w += (size_t)BDIM * LDIM * DIN;
    unsigned short* xT16  = w; w += (size_t)BDIM * DIN * LDIM;
    unsigned short* WqC   = w; w += (size_t)DIN * HDIM * DK;
    unsigned short* WkT   = w; w += (size_t)HDIM * DK * DIN;
    unsigned short* WvT   = w; w += (size_t)HDIM * DV * DIN;
    unsigned short* WoT   = w; w += (size_t)HDIM * DOUT * DV;
    unsigned short* G16   = w; w += (size_t)BDIM * DIN * DIN;
    unsigned short* UT    = w; w += (size_t)BDIM * DIN * DIN;
    unsigned short* NT    = w; w += (size_t)BDIM * DOUT * DIN;
    unsigned short* CT    = w; w += (size_t)BDIM * DIN * DOUT;
    float* Gp = (float*)(((uintptr_t)w + 255) & ~(uintptr_t)255);  // BDIM*NS*512*512 f32

    k_prep2<<<dim3(1280), 256, 0, stream>>>(x, Wq, Wk, Wv, Wo, xb16, xT16,
                                            WqC, WkT, WvT, WoT);
    k_gram<<<dim3(4, 4, BDIM * NS), 256, 0, stream>>>((const bf16_t*)xT16, Gp);
    k_gred<<<dim3((BDIM * DIN * DIN) / 1024), 256, 0, stream>>>(Gp, G16);
    k_proj<<<dim3(8, 8, BDIM), 256, 0, stream>>>((const bf16_t*)G16,
                                                 (const bf16_t*)WvT, UT);
    k_kvnw<<<dim3(8, BDIM * HDIM), 256, 0, stream>>>((const bf16_t*)WkT,
                                                     (const bf16_t*)UT,
                                                     (const bf16_t*)WoT, NT);
    k_cw<<<dim3(8, 8, BDIM), 256, 0, stream>>>((const bf16_t*)WqC,
                                               (const bf16_t*)NT, CT);
    k_out<<<dim3(LDIM / 128, DOUT / 128, BDIM), 256, 0, stream>>>(
        (const bf16_t*)xb16, (const bf16_t*)CT, out);
}

// Round 6
// 131.534 us; speedup vs baseline: 2.4385x; 1.0147x over previous
//
#include <hip/hip_runtime.h>
#include <cstdint>

// out[b] = x[b] @ C[b],  C[b] = sum_h Wq[h] (Wk[h]^T G[b] Wv[h]) Wo[h],
// G[b] = x[b]^T x[b].  bf16 MFMA 16x16x32, fp32 accum.
// R6: NS=16 gram with bf16 partials (512 blocks = 2/CU); k_m+k_tail replace
// kvnw+cw (M tiny in LDS, CT computed directly); k_out 64x128 tiles (2/CU).

#define BDIM 2
#define LDIM 4096
#define DIN 512
#define HDIM 8
#define DK 64
#define DV 64
#define DOUT 512
#define NS 16  // split-K slices for gram

using bf16_t = __bf16;
typedef __bf16 bf16x8 __attribute__((ext_vector_type(8)));
typedef float floatx4 __attribute__((ext_vector_type(4)));

__device__ __forceinline__ unsigned short f2bf(float f) {
    unsigned int u = __builtin_bit_cast(unsigned int, f);
    u += 0x7FFFu + ((u >> 16) & 1u);
    return (unsigned short)(u >> 16);
}

__device__ __forceinline__ float bf2f(unsigned short s) {
    unsigned int u = ((unsigned int)s) << 16;
    return __builtin_bit_cast(float, u);
}

__device__ __forceinline__ void gld_lds16(const void* g, void* l) {
    __builtin_amdgcn_global_load_lds(
        (const __attribute__((address_space(1))) void*)g,
        (__attribute__((address_space(3))) void*)l, 16, 0, 0);
}

// ---------------- generic TN MFMA GEMM core ----------------
// C[m][n] = sum_k A[m][k]*B[n][k]; A,B k-contiguous bf16. 256 thr, 2x2 waves.
// OUT_MODE: 0 = f32 store, 1 = bf16 store.
template <int BM, int BN, int BK, bool TRANS_OUT, int OUT_MODE>
__device__ __forceinline__ void gemm_core(const bf16_t* A, const bf16_t* B,
                                          void* Cp, int K, int lda, int ldb,
                                          int ldc, int tm, int tn) {
    constexpr int WM = BM / 2, WN = BN / 2;
    constexpr int FM = WM / 16, FN = WN / 16;
    constexpr int CPR = BK / 8;  // 16B chunks per row
    __shared__ bf16_t As[BM * BK];
    __shared__ bf16_t Bs[BN * BK];
    const int tid = threadIdx.x;
    const int lane = tid & 63;
    const int wr = (tid >> 7) & 1;
    const int wc = (tid >> 6) & 1;

    A += (size_t)tm * lda;
    B += (size_t)tn * ldb;

    floatx4 acc[FM][FN] = {};

    for (int k0 = 0; k0 < K; k0 += BK) {
#pragma unroll
        for (int i = 0; i < (BM * CPR) / 256; ++i) {
            int c = i * 256 + tid;
            int m = c / CPR, kc = c % CPR;
            gld_lds16(A + (size_t)m * lda + k0 + kc * 8, As + c * 8);
        }
#pragma unroll
        for (int i = 0; i < (BN * CPR) / 256; ++i) {
            int c = i * 256 + tid;
            int m = c / CPR, kc = c % CPR;
            gld_lds16(B + (size_t)m * ldb + k0 + kc * 8, Bs + c * 8);
        }
        __syncthreads();

#pragma unroll
        for (int kk = 0; kk < BK; kk += 32) {
            bf16x8 aF[FM], bF[FN];
#pragma unroll
            for (int fm = 0; fm < FM; ++fm)
                aF[fm] = *(const bf16x8*)(As + (wr * WM + fm * 16 + (lane & 15)) * BK +
                                          kk + (lane >> 4) * 8);
#pragma unroll
            for (int fn = 0; fn < FN; ++fn)
                bF[fn] = *(const bf16x8*)(Bs + (wc * WN + fn * 16 + (lane & 15)) * BK +
                                          kk + (lane >> 4) * 8);
#pragma unroll
            for (int fm = 0; fm < FM; ++fm)
#pragma unroll
                for (int fn = 0; fn < FN; ++fn)
                    acc[fm][fn] = __builtin_amdgcn_mfma_f32_16x16x32_bf16(
                        aF[fm], bF[fn], acc[fm][fn], 0, 0, 0);
        }
        __syncthreads();
    }

    const int cr4 = (lane >> 4) * 4;
    const int cn = lane & 15;
#pragma unroll
    for (int fm = 0; fm < FM; ++fm)
#pragma unroll
        for (int fn = 0; fn < FN; ++fn)
#pragma unroll
            for (int r = 0; r < 4; ++r) {
                int m = tm + wr * WM + fm * 16 + cr4 + r;
                int n = tn + wc * WN + fn * 16 + cn;
                size_t idx = TRANS_OUT ? ((size_t)n * ldc + m)
                                       : ((size_t)m * ldc + n);
                if (OUT_MODE == 0)
                    ((float*)Cp)[idx] = acc[fm][fn][r];
                else
                    ((unsigned short*)Cp)[idx] = f2bf(acc[fm][fn][r]);
            }
}

// ---- gram: Gp[b,s] = xT[b] slice @ slice^T (bf16 partial) ----
__global__ __launch_bounds__(256) void k_gram(const bf16_t* xT, unsigned short* Gp) {
    int z = blockIdx.z, b = z / NS, s = z % NS;
    const bf16_t* Ab = xT + (size_t)b * DIN * LDIM + s * (LDIM / NS);
    gemm_core<128, 128, 64, false, 1>(Ab, Ab, Gp + (size_t)z * DIN * DIN,
                                      LDIM / NS, LDIM, LDIM, DIN,
                                      blockIdx.x * 128, blockIdx.y * 128);
}

// ---- reduce NS bf16 partials -> bf16 G (8 elems/thread) ----
__global__ __launch_bounds__(256) void k_gred(const unsigned short* Gp,
                                              unsigned short* G16) {
    size_t gid = (size_t)blockIdx.x * 256 + threadIdx.x;
    int b = (int)(gid >> 15);                 // 32768 threads per batch
    size_t r = (gid & 32767) * 8;
    float s[8] = {};
#pragma unroll
    for (int sl = 0; sl < NS; ++sl) {
        const unsigned short* p = Gp + (((size_t)(b * NS + sl)) << 18) + r;
        uint4 v = *(const uint4*)p;
        unsigned int ws[4] = {v.x, v.y, v.z, v.w};
#pragma unroll
        for (int q = 0; q < 4; ++q) {
            s[q * 2 + 0] += bf2f((unsigned short)(ws[q] & 0xffffu));
            s[q * 2 + 1] += bf2f((unsigned short)(ws[q] >> 16));
        }
    }
    unsigned short o[8];
#pragma unroll
    for (int q = 0; q < 8; ++q) o[q] = f2bf(s[q]);
    *(uint4*)(G16 + (((size_t)b) << 18) + r) = *(const uint4*)o;
}

// ---- U_all[b] = G[b] @ Wv_cat, stored transposed UT[b][h*64+v][i] ----
__global__ __launch_bounds__(256) void k_proj(const bf16_t* G16, const bf16_t* WvT,
                                              unsigned short* UT) {
    int b = blockIdx.z;
    gemm_core<64, 64, 32, true, 1>(G16 + (size_t)b * DIN * DIN, WvT,
                                   UT + (size_t)b * DIN * DIN, DIN, DIN, DIN,
                                   DIN, blockIdx.x * 64, blockIdx.y * 64);
}

// ---- k_m: M[b,h] = WkT[h] @ U[b,h], natural [dk][v] bf16 ----
__global__ __launch_bounds__(256) void k_m(const bf16_t* WkT, const bf16_t* UT,
                                           unsigned short* M) {
    int z = blockIdx.x, b = z >> 3, h = z & 7;
    gemm_core<64, 64, 32, false, 1>(WkT + (size_t)h * DK * DIN,
                                    UT + (size_t)b * DIN * DIN + (size_t)h * DV * DIN,
                                    M + (size_t)z * DK * DV, DIN, DIN, DIN, DV,
                                    0, 0);
}

// ---- k_tail: CT[b][o][i] = sum_h sum_dk PT[h][o][dk] * Wq[h][i][dk]
//      where PT[h][o][dk] = sum_v WoT[h][o][v] * M[b,h][dk][v]
__global__ __launch_bounds__(256) void k_tail(const bf16_t* WqC, const bf16_t* WoT,
                                              const bf16_t* M, unsigned short* CT) {
    int i0 = blockIdx.x * 64, o0 = blockIdx.y * 64, b = blockIdx.z;
    __shared__ bf16_t Aq[64 * 64];   // Wq rows i, k=dk
    __shared__ bf16_t Ws[64 * 64];   // WoT rows o, k=v
    __shared__ bf16_t Msh[64 * 64];  // M rows dk, k=v
    __shared__ bf16_t PTs[64 * 64];  // PT rows o, k=dk
    const int tid = threadIdx.x;
    const int lane = tid & 63;
    const int wr = (tid >> 7) & 1, wc = (tid >> 6) & 1;
    const int cr4 = (lane >> 4) * 4, cn = lane & 15;

    floatx4 acc[2][2] = {};

    for (int h = 0; h < HDIM; ++h) {
        // stage Wq slab (rows i0.., cols h*64..), Wo slab (rows o0..), M[b,h]
#pragma unroll
        for (int i = 0; i < 2; ++i) {
            int c = i * 256 + tid, m = c >> 3, kc = c & 7;
            gld_lds16(WqC + (size_t)(i0 + m) * DIN + h * 64 + kc * 8, Aq + c * 8);
            gld_lds16(WoT + ((size_t)h * DOUT + o0 + m) * DV + kc * 8, Ws + c * 8);
            gld_lds16(M + (((size_t)(b * HDIM + h)) << 12) + m * 64 + kc * 8,
                      Msh + c * 8);
        }
        __syncthreads();

        // MFMA1: PT[o][dk] = sum_v Ws[o][v] * Msh[dk][v]
        floatx4 pt[2][2] = {};
#pragma unroll
        for (int kk = 0; kk < 64; kk += 32) {
            bf16x8 aF[2], bF[2];
#pragma unroll
            for (int f = 0; f < 2; ++f) {
                aF[f] = *(const bf16x8*)(Ws + (wr * 32 + f * 16 + cn) * 64 + kk +
                                         (lane >> 4) * 8);
                bF[f] = *(const bf16x8*)(Msh + (wc * 32 + f * 16 + cn) * 64 + kk +
                                         (lane >> 4) * 8);
            }
#pragma unroll
            for (int fm = 0; fm < 2; ++fm)
#pragma unroll
                for (int fn = 0; fn < 2; ++fn)
                    pt[fm][fn] = __builtin_amdgcn_mfma_f32_16x16x32_bf16(
                        aF[fm], bF[fn], pt[fm][fn], 0, 0, 0);
        }
#pragma unroll
        for (int fm = 0; fm < 2; ++fm)
#pragma unroll
            for (int fn = 0; fn < 2; ++fn)
#pragma unroll
                for (int r = 0; r < 4; ++r) {
                    int m = wr * 32 + fm * 16 + cr4 + r;
                    int n = wc * 32 + fn * 16 + cn;
                    ((unsigned short*)PTs)[m * 64 + n] = f2bf(pt[fm][fn][r]);
                }
        __syncthreads();

        // MFMA2: acc[o][i] += sum_dk PTs[o][dk] * Aq[i][dk]
#pragma unroll
        for (int kk = 0; kk < 64; kk += 32) {
            bf16x8 aF[2], bF[2];
#pragma unroll
            for (int f = 0; f < 2; ++f) {
                aF[f] = *(const bf16x8*)(PTs + (wr * 32 + f * 16 + cn) * 64 + kk +
                                         (lane >> 4) * 8);
                bF[f] = *(const bf16x8*)(Aq + (wc * 32 + f * 16 + cn) * 64 + kk +
                                         (lane >> 4) * 8);
            }
#pragma unroll
            for (int fm = 0; fm < 2; ++fm)
#pragma unroll
                for (int fn = 0; fn < 2; ++fn)
                    acc[fm][fn] = __builtin_amdgcn_mfma_f32_16x16x32_bf16(
                        aF[fm], bF[fn], acc[fm][fn], 0, 0, 0);
        }
        __syncthreads();
    }

    // write CT[b][o0+m][i0+n], i contiguous
    unsigned short* CTb = CT + (size_t)b * DIN * DOUT;
#pragma unroll
    for (int fm = 0; fm < 2; ++fm)
#pragma unroll
        for (int fn = 0; fn < 2; ++fn)
#pragma unroll
            for (int r = 0; r < 4; ++r) {
                int m = wr * 32 + fm * 16 + cr4 + r;
                int n = wc * 32 + fn * 16 + cn;
                CTb[(size_t)(o0 + m) * DIN + i0 + n] = f2bf(acc[fm][fn][r]);
            }
}

// ---- out[b] = x16[b] @ C[b], fp32 out, 64x128 tiles (2 blocks/CU) ----
__global__ __launch_bounds__(256) void k_out(const bf16_t* x16, const bf16_t* CT,
                                             float* out) {
    int b = blockIdx.z;
    gemm_core<64, 128, 64, false, 0>(x16 + (size_t)b * LDIM * DIN,
                                     CT + (size_t)b * DIN * DOUT,
                                     out + (size_t)b * LDIM * DOUT, DIN, DIN,
                                     DIN, DOUT, blockIdx.x * 64,
                                     blockIdx.y * 128);
}

// ---------------- merged prep: x convert+transpose AND weight prep ----------------
__global__ __launch_bounds__(256) void k_prep2(
    const float* x, const float* Wq, const float* Wk, const float* Wv,
    const float* Wo, unsigned short* xb, unsigned short* xT,
    unsigned short* WqC, unsigned short* WkT, unsigned short* WvT,
    unsigned short* WoT) {
    __shared__ unsigned short T[64][65];
    int tr = threadIdx.x >> 4, tc4 = (threadIdx.x & 15) * 4;
    int bid = blockIdx.x;
    if (bid < 1024) {
        int b = bid >> 9, r = bid & 511;
        int d0 = (r & 7) * 64, l0 = (r >> 3) * 64;
        const float* xp = x + (size_t)b * LDIM * DIN;
        unsigned short* xbp = xb + (size_t)b * LDIM * DIN;
#pragma unroll
        for (int p = 0; p < 4; ++p) {
            int l = p * 16 + tr;
            float4 v = *(const float4*)(xp + (size_t)(l0 + l) * DIN + d0 + tc4);
            unsigned short q0 = f2bf(v.x), q1 = f2bf(v.y), q2 = f2bf(v.z),
                           q3 = f2bf(v.w);
            *(ushort4*)(xbp + (size_t)(l0 + l) * DIN + d0 + tc4) =
                make_ushort4(q0, q1, q2, q3);
            T[l][tc4 + 0] = q0; T[l][tc4 + 1] = q1;
            T[l][tc4 + 2] = q2; T[l][tc4 + 3] = q3;
        }
        __syncthreads();
        unsigned short* xTp = xT + (size_t)b * DIN * LDIM;
#pragma unroll
        for (int p = 0; p < 4; ++p) {
            int d = p * 16 + tr;
            ushort4 u = make_ushort4(T[tc4 + 0][d], T[tc4 + 1][d], T[tc4 + 2][d],
                                     T[tc4 + 3][d]);
            *(ushort4*)(xTp + (size_t)(d0 + d) * LDIM + l0 + tc4) = u;
        }
        return;
    }
    int p_ = bid - 1024;
    int t = p_ & 7, job = (p_ >> 3) & 3, h = p_ >> 5;
    if (job == 0) {
        const float* src = Wq + (size_t)h * DIN * DK;
#pragma unroll
        for (int p = 0; p < 4; ++p) {
            int i = t * 64 + p * 16 + tr;
            float4 v = *(const float4*)(src + (size_t)i * DK + tc4);
            *(ushort4*)(WqC + (size_t)i * (HDIM * DK) + h * DK + tc4) =
                make_ushort4(f2bf(v.x), f2bf(v.y), f2bf(v.z), f2bf(v.w));
        }
        return;
    }
    const float* src;
    unsigned short* dst;
    int rows, cols, r0, c0;
    if (job == 1) {
        src = Wk + (size_t)h * DIN * DK; dst = WkT + (size_t)h * DK * DIN;
        rows = DIN; cols = DK; r0 = t * 64; c0 = 0;
    } else if (job == 2) {
        src = Wv + (size_t)h * DIN * DV; dst = WvT + (size_t)h * DV * DIN;
        rows = DIN; cols = DV; r0 = t * 64; c0 = 0;
    } else {
        src = Wo + (size_t)h * DV * DOUT; dst = WoT + (size_t)h * DOUT * DV;
        rows = DV; cols = DOUT; r0 = 0; c0 = t * 64;
    }
#pragma unroll
    for (int p = 0; p < 4; ++p) {
        int r = p * 16 + tr;
        float4 v = *(const float4*)(src + (size_t)(r0 + r) * cols + c0 + tc4);
        T[r][tc4 + 0] = f2bf(v.x); T[r][tc4 + 1] = f2bf(v.y);
        T[r][tc4 + 2] = f2bf(v.z); T[r][tc4 + 3] = f2bf(v.w);
    }
    __syncthreads();
#pragma unroll
    for (int p = 0; p < 4; ++p) {
        int c = p * 16 + tr;
        ushort4 u = make_ushort4(T[tc4 + 0][c], T[tc4 + 1][c], T[tc4 + 2][c],
                                 T[tc4 + 3][c]);
        *(ushort4*)(dst + (size_t)(c0 + c) * rows + r0 + tc4) = u;
    }
}

extern "C" void kernel_launch(void* const* d_in, const int* in_sizes, int n_in,
                              void* d_out, int out_size, void* d_ws, size_t ws_size,
                              hipStream_t stream) {
    const float* x  = (const float*)d_in[0];
    const float* Wq = (const float*)d_in[1];
    const float* Wk = (const float*)d_in[2];
    const float* Wv = (const float*)d_in[3];
    const float* Wo = (const float*)d_in[4];
    float* out = (float*)d_out;

    unsigned short* w = (unsigned short*)d_ws;
    unsigned short* xb16  = w; w += (size_t)BDIM * LDIM * DIN;
    unsigned short* xT16  = w; w += (size_t)BDIM * DIN * LDIM;
    unsigned short* WqC   = w; w += (size_t)DIN * HDIM * DK;
    unsigned short* WkT   = w; w += (size_t)HDIM * DK * DIN;
    unsigned short* WvT   = w; w += (size_t)HDIM * DV * DIN;
    unsigned short* WoT   = w; w += (size_t)HDIM * DOUT * DV;
    unsigned short* G16   = w; w += (size_t)BDIM * DIN * DIN;
    unsigned short* UT    = w; w += (size_t)BDIM * DIN * DIN;
    unsigned short* Mbuf  = w; w += (size_t)BDIM * HDIM * DK * DV;
    unsigned short* CT    = w; w += (size_t)BDIM * DIN * DOUT;
    unsigned short* Gp    = w; w += (size_t)BDIM * NS * DIN * DIN;

    k_prep2<<<dim3(1280), 256, 0, stream>>>(x, Wq, Wk, Wv, Wo, xb16, xT16,
                                            WqC, WkT, WvT, WoT);
    k_gram<<<dim3(4, 4, BDIM * NS), 256, 0, stream>>>((const bf16_t*)xT16, Gp);
    k_gred<<<dim3((BDIM * DIN * DIN) / (256 * 8)), 256, 0, stream>>>(Gp, G16);
    k_proj<<<dim3(8, 8, BDIM), 256, 0, stream>>>((const bf16_t*)G16,
                                                 (const bf16_t*)WvT, UT);
    k_m<<<dim3(BDIM * HDIM), 256, 0, stream>>>((const bf16_t*)WkT,
                                               (const bf16_t*)UT, Mbuf);
    k_tail<<<dim3(8, 8, BDIM), 256, 0, stream>>>((const bf16_t*)WqC,
                                                 (const bf16_t*)WoT,
                                                 (const bf16_t*)Mbuf, CT);
    k_out<<<dim3(LDIM / 64, DOUT / 128, BDIM), 256, 0, stream>>>(
        (const bf16_t*)xb16, (const bf16_t*)CT, out);
}

// Round 7
// 128.512 us; speedup vs baseline: 2.4958x; 1.0235x over previous
//
#include <hip/hip_runtime.h>
#include <cstdint>

// out[b] = x[b] @ C[b],  C[b] = sum_h Wq[h] (Wk[h]^T G[b] Wv[h]) Wo[h],
// G[b] = x[b]^T x[b].  bf16 MFMA 16x16x32, fp32 accum.
// R7: 6 kernels. k_m folded into k_proj (U-tile -> LDS -> x WkT slice ->
// fp32 atomic partials of M); UT global buffer eliminated; prep2 zeroes M32;
// tail stages M from fp32 inline.

#define BDIM 2
#define LDIM 4096
#define DIN 512
#define HDIM 8
#define DK 64
#define DV 64
#define DOUT 512
#define NS 16  // split-K slices for gram

using bf16_t = __bf16;
typedef __bf16 bf16x8 __attribute__((ext_vector_type(8)));
typedef float floatx4 __attribute__((ext_vector_type(4)));

__device__ __forceinline__ unsigned short f2bf(float f) {
    unsigned int u = __builtin_bit_cast(unsigned int, f);
    u += 0x7FFFu + ((u >> 16) & 1u);
    return (unsigned short)(u >> 16);
}

__device__ __forceinline__ float bf2f(unsigned short s) {
    unsigned int u = ((unsigned int)s) << 16;
    return __builtin_bit_cast(float, u);
}

__device__ __forceinline__ void gld_lds16(const void* g, void* l) {
    __builtin_amdgcn_global_load_lds(
        (const __attribute__((address_space(1))) void*)g,
        (__attribute__((address_space(3))) void*)l, 16, 0, 0);
}

// ---------------- generic TN MFMA GEMM core ----------------
// C[m][n] = sum_k A[m][k]*B[n][k]; A,B k-contiguous bf16. 256 thr, 2x2 waves.
// OUT_MODE: 0 = f32 store, 1 = bf16 store.
template <int BM, int BN, int BK, bool TRANS_OUT, int OUT_MODE>
__device__ __forceinline__ void gemm_core(const bf16_t* A, const bf16_t* B,
                                          void* Cp, int K, int lda, int ldb,
                                          int ldc, int tm, int tn) {
    constexpr int WM = BM / 2, WN = BN / 2;
    constexpr int FM = WM / 16, FN = WN / 16;
    constexpr int CPR = BK / 8;  // 16B chunks per row
    __shared__ bf16_t As[BM * BK];
    __shared__ bf16_t Bs[BN * BK];
    const int tid = threadIdx.x;
    const int lane = tid & 63;
    const int wr = (tid >> 7) & 1;
    const int wc = (tid >> 6) & 1;

    A += (size_t)tm * lda;
    B += (size_t)tn * ldb;

    floatx4 acc[FM][FN] = {};

    for (int k0 = 0; k0 < K; k0 += BK) {
#pragma unroll
        for (int i = 0; i < (BM * CPR) / 256; ++i) {
            int c = i * 256 + tid;
            int m = c / CPR, kc = c % CPR;
            gld_lds16(A + (size_t)m * lda + k0 + kc * 8, As + c * 8);
        }
#pragma unroll
        for (int i = 0; i < (BN * CPR) / 256; ++i) {
            int c = i * 256 + tid;
            int m = c / CPR, kc = c % CPR;
            gld_lds16(B + (size_t)m * ldb + k0 + kc * 8, Bs + c * 8);
        }
        __syncthreads();

#pragma unroll
        for (int kk = 0; kk < BK; kk += 32) {
            bf16x8 aF[FM], bF[FN];
#pragma unroll
            for (int fm = 0; fm < FM; ++fm)
                aF[fm] = *(const bf16x8*)(As + (wr * WM + fm * 16 + (lane & 15)) * BK +
                                          kk + (lane >> 4) * 8);
#pragma unroll
            for (int fn = 0; fn < FN; ++fn)
                bF[fn] = *(const bf16x8*)(Bs + (wc * WN + fn * 16 + (lane & 15)) * BK +
                                          kk + (lane >> 4) * 8);
#pragma unroll
            for (int fm = 0; fm < FM; ++fm)
#pragma unroll
                for (int fn = 0; fn < FN; ++fn)
                    acc[fm][fn] = __builtin_amdgcn_mfma_f32_16x16x32_bf16(
                        aF[fm], bF[fn], acc[fm][fn], 0, 0, 0);
        }
        __syncthreads();
    }

    const int cr4 = (lane >> 4) * 4;
    const int cn = lane & 15;
#pragma unroll
    for (int fm = 0; fm < FM; ++fm)
#pragma unroll
        for (int fn = 0; fn < FN; ++fn)
#pragma unroll
            for (int r = 0; r < 4; ++r) {
                int m = tm + wr * WM + fm * 16 + cr4 + r;
                int n = tn + wc * WN + fn * 16 + cn;
                size_t idx = TRANS_OUT ? ((size_t)n * ldc + m)
                                       : ((size_t)m * ldc + n);
                if (OUT_MODE == 0)
                    ((float*)Cp)[idx] = acc[fm][fn][r];
                else
                    ((unsigned short*)Cp)[idx] = f2bf(acc[fm][fn][r]);
            }
}

// ---- gram: Gp[b,s] = xT[b] slice @ slice^T (bf16 partial) ----
__global__ __launch_bounds__(256) void k_gram(const bf16_t* xT, unsigned short* Gp) {
    int z = blockIdx.z, b = z / NS, s = z % NS;
    const bf16_t* Ab = xT + (size_t)b * DIN * LDIM + s * (LDIM / NS);
    gemm_core<128, 128, 64, false, 1>(Ab, Ab, Gp + (size_t)z * DIN * DIN,
                                      LDIM / NS, LDIM, LDIM, DIN,
                                      blockIdx.x * 128, blockIdx.y * 128);
}

// ---- reduce NS bf16 partials -> bf16 G (8 elems/thread) ----
__global__ __launch_bounds__(256) void k_gred(const unsigned short* Gp,
                                              unsigned short* G16) {
    size_t gid = (size_t)blockIdx.x * 256 + threadIdx.x;
    int b = (int)(gid >> 15);                 // 32768 threads per batch
    size_t r = (gid & 32767) * 8;
    float s[8] = {};
#pragma unroll
    for (int sl = 0; sl < NS; ++sl) {
        const unsigned short* p = Gp + (((size_t)(b * NS + sl)) << 18) + r;
        uint4 v = *(const uint4*)p;
        unsigned int ws[4] = {v.x, v.y, v.z, v.w};
#pragma unroll
        for (int q = 0; q < 4; ++q) {
            s[q * 2 + 0] += bf2f((unsigned short)(ws[q] & 0xffffu));
            s[q * 2 + 1] += bf2f((unsigned short)(ws[q] >> 16));
        }
    }
    unsigned short o[8];
#pragma unroll
    for (int q = 0; q < 8; ++q) o[q] = f2bf(s[q]);
    *(uint4*)(G16 + (((size_t)b) << 18) + r) = *(const uint4*)o;
}

// ---- k_proj: U-tile = G rows[i0..i0+64) @ Wv[h]  (K=512), then
//      M32[b,h] += WkT[h][:, i0..i0+64) @ U-tile  (fp32 atomics) ----
__global__ __launch_bounds__(256) void k_proj(const bf16_t* G16, const bf16_t* WvT,
                                              const bf16_t* WkT, float* M32) {
    int i0 = blockIdx.x * 64, h = blockIdx.y, b = blockIdx.z;
    __shared__ bf16_t As[64 * 32];
    __shared__ bf16_t Bs[64 * 32];
    __shared__ bf16_t Us[64 * 64];  // U-tile transposed: [v][i]
    __shared__ bf16_t Ks[64 * 64];  // WkT slice: [dk][i]
    const int tid = threadIdx.x;
    const int lane = tid & 63;
    const int wr = (tid >> 7) & 1, wc = (tid >> 6) & 1;
    const int cr4 = (lane >> 4) * 4, cn = lane & 15;

    // stage 1: U[i][v] = sum_j G[i0+i][j] * WvT[h*64+v][j]
    const bf16_t* A = G16 + (size_t)b * DIN * DIN + (size_t)i0 * DIN;
    const bf16_t* B = WvT + (size_t)h * DV * DIN;
    floatx4 acc[2][2] = {};
    for (int k0 = 0; k0 < DIN; k0 += 32) {
        int m = tid >> 2, kc = tid & 3;
        gld_lds16(A + (size_t)m * DIN + k0 + kc * 8, As + tid * 8);
        gld_lds16(B + (size_t)m * DIN + k0 + kc * 8, Bs + tid * 8);
        __syncthreads();
        bf16x8 aF[2], bF[2];
#pragma unroll
        for (int f = 0; f < 2; ++f) {
            aF[f] = *(const bf16x8*)(As + (wr * 32 + f * 16 + cn) * 32 + (lane >> 4) * 8);
            bF[f] = *(const bf16x8*)(Bs + (wc * 32 + f * 16 + cn) * 32 + (lane >> 4) * 8);
        }
#pragma unroll
        for (int fm = 0; fm < 2; ++fm)
#pragma unroll
            for (int fn = 0; fn < 2; ++fn)
                acc[fm][fn] = __builtin_amdgcn_mfma_f32_16x16x32_bf16(
                    aF[fm], bF[fn], acc[fm][fn], 0, 0, 0);
        __syncthreads();
    }
    // write U-tile transposed to LDS: Us[v][i]
#pragma unroll
    for (int fm = 0; fm < 2; ++fm)
#pragma unroll
        for (int fn = 0; fn < 2; ++fn)
#pragma unroll
            for (int r = 0; r < 4; ++r) {
                int m = wr * 32 + fm * 16 + cr4 + r;   // i local
                int n = wc * 32 + fn * 16 + cn;        // v local
                ((unsigned short*)Us)[n * 64 + m] = f2bf(acc[fm][fn][r]);
            }
    // stage WkT slice: rows dk(64) x cols [i0, i0+64)
#pragma unroll
    for (int i = 0; i < 2; ++i) {
        int c = i * 256 + tid, m = c >> 3, kc = c & 7;
        gld_lds16(WkT + (size_t)h * DK * DIN + (size_t)m * DIN + i0 + kc * 8,
                  Ks + c * 8);
    }
    __syncthreads();

    // stage 2: M_part[dk][v] = sum_i Ks[dk][i] * Us[v][i]  (K=64)
    floatx4 mm[2][2] = {};
#pragma unroll
    for (int kk = 0; kk < 64; kk += 32) {
        bf16x8 aF[2], bF[2];
#pragma unroll
        for (int f = 0; f < 2; ++f) {
            aF[f] = *(const bf16x8*)(Ks + (wr * 32 + f * 16 + cn) * 64 + kk +
                                     (lane >> 4) * 8);
            bF[f] = *(const bf16x8*)(Us + (wc * 32 + f * 16 + cn) * 64 + kk +
                                     (lane >> 4) * 8);
        }
#pragma unroll
        for (int fm = 0; fm < 2; ++fm)
#pragma unroll
            for (int fn = 0; fn < 2; ++fn)
                mm[fm][fn] = __builtin_amdgcn_mfma_f32_16x16x32_bf16(
                    aF[fm], bF[fn], mm[fm][fn], 0, 0, 0);
    }
    float* Mh = M32 + ((size_t)(b * HDIM + h)) * (DK * DV);
#pragma unroll
    for (int fm = 0; fm < 2; ++fm)
#pragma unroll
        for (int fn = 0; fn < 2; ++fn)
#pragma unroll
            for (int r = 0; r < 4; ++r) {
                int m = wr * 32 + fm * 16 + cr4 + r;   // dk
                int n = wc * 32 + fn * 16 + cn;        // v
                atomicAdd(&Mh[m * 64 + n], mm[fm][fn][r]);
            }
}

// ---- k_tail: CT[b][o][i] = sum_h sum_dk PT[h][o][dk] * Wq[h][i][dk]
//      where PT[h][o][dk] = sum_v WoT[h][o][v] * M[b,h][dk][v]
__global__ __launch_bounds__(256) void k_tail(const bf16_t* WqC, const bf16_t* WoT,
                                              const float* M32, unsigned short* CT) {
    int i0 = blockIdx.x * 64, o0 = blockIdx.y * 64, b = blockIdx.z;
    __shared__ bf16_t Aq[64 * 64];   // Wq rows i, k=dk
    __shared__ bf16_t Ws[64 * 64];   // WoT rows o, k=v
    __shared__ bf16_t Msh[64 * 64];  // M rows dk, k=v
    __shared__ bf16_t PTs[64 * 64];  // PT rows o, k=dk
    const int tid = threadIdx.x;
    const int lane = tid & 63;
    const int wr = (tid >> 7) & 1, wc = (tid >> 6) & 1;
    const int cr4 = (lane >> 4) * 4, cn = lane & 15;

    floatx4 acc[2][2] = {};

    for (int h = 0; h < HDIM; ++h) {
        // stage Wq slab (rows i0.., cols h*64..), Wo slab (rows o0..)
#pragma unroll
        for (int i = 0; i < 2; ++i) {
            int c = i * 256 + tid, m = c >> 3, kc = c & 7;
            gld_lds16(WqC + (size_t)(i0 + m) * DIN + h * 64 + kc * 8, Aq + c * 8);
            gld_lds16(WoT + ((size_t)h * DOUT + o0 + m) * DV + kc * 8, Ws + c * 8);
        }
        // stage M[b,h] from fp32 with inline convert
        const float* Mh = M32 + ((size_t)(b * HDIM + h)) * (DK * DV);
#pragma unroll
        for (int i = 0; i < 4; ++i) {
            int idx = (i * 256 + tid) * 4;
            float4 v = *(const float4*)(Mh + idx);
            *(ushort4*)((unsigned short*)Msh + idx) =
                make_ushort4(f2bf(v.x), f2bf(v.y), f2bf(v.z), f2bf(v.w));
        }
        __syncthreads();

        // MFMA1: PT[o][dk] = sum_v Ws[o][v] * Msh[dk][v]
        floatx4 pt[2][2] = {};
#pragma unroll
        for (int kk = 0; kk < 64; kk += 32) {
            bf16x8 aF[2], bF[2];
#pragma unroll
            for (int f = 0; f < 2; ++f) {
                aF[f] = *(const bf16x8*)(Ws + (wr * 32 + f * 16 + cn) * 64 + kk +
                                         (lane >> 4) * 8);
                bF[f] = *(const bf16x8*)(Msh + (wc * 32 + f * 16 + cn) * 64 + kk +
                                         (lane >> 4) * 8);
            }
#pragma unroll
            for (int fm = 0; fm < 2; ++fm)
#pragma unroll
                for (int fn = 0; fn < 2; ++fn)
                    pt[fm][fn] = __builtin_amdgcn_mfma_f32_16x16x32_bf16(
                        aF[fm], bF[fn], pt[fm][fn], 0, 0, 0);
        }
#pragma unroll
        for (int fm = 0; fm < 2; ++fm)
#pragma unroll
            for (int fn = 0; fn < 2; ++fn)
#pragma unroll
                for (int r = 0; r < 4; ++r) {
                    int m = wr * 32 + fm * 16 + cr4 + r;
                    int n = wc * 32 + fn * 16 + cn;
                    ((unsigned short*)PTs)[m * 64 + n] = f2bf(pt[fm][fn][r]);
                }
        __syncthreads();

        // MFMA2: acc[o][i] += sum_dk PTs[o][dk] * Aq[i][dk]
#pragma unroll
        for (int kk = 0; kk < 64; kk += 32) {
            bf16x8 aF[2], bF[2];
#pragma unroll
            for (int f = 0; f < 2; ++f) {
                aF[f] = *(const bf16x8*)(PTs + (wr * 32 + f * 16 + cn) * 64 + kk +
                                         (lane >> 4) * 8);
                bF[f] = *(const bf16x8*)(Aq + (wc * 32 + f * 16 + cn) * 64 + kk +
                                         (lane >> 4) * 8);
            }
#pragma unroll
            for (int fm = 0; fm < 2; ++fm)
#pragma unroll
                for (int fn = 0; fn < 2; ++fn)
                    acc[fm][fn] = __builtin_amdgcn_mfma_f32_16x16x32_bf16(
                        aF[fm], bF[fn], acc[fm][fn], 0, 0, 0);
        }
        __syncthreads();
    }

    // write CT[b][o0+m][i0+n], i contiguous
    unsigned short* CTb = CT + (size_t)b * DIN * DOUT;
#pragma unroll
    for (int fm = 0; fm < 2; ++fm)
#pragma unroll
        for (int fn = 0; fn < 2; ++fn)
#pragma unroll
            for (int r = 0; r < 4; ++r) {
                int m = wr * 32 + fm * 16 + cr4 + r;
                int n = wc * 32 + fn * 16 + cn;
                CTb[(size_t)(o0 + m) * DIN + i0 + n] = f2bf(acc[fm][fn][r]);
            }
}

// ---- out[b] = x16[b] @ C[b], fp32 out, 64x128 tiles (2 blocks/CU) ----
__global__ __launch_bounds__(256) void k_out(const bf16_t* x16, const bf16_t* CT,
                                             float* out) {
    int b = blockIdx.z;
    gemm_core<64, 128, 64, false, 0>(x16 + (size_t)b * LDIM * DIN,
                                     CT + (size_t)b * DIN * DOUT,
                                     out + (size_t)b * LDIM * DOUT, DIN, DIN,
                                     DIN, DOUT, blockIdx.x * 64,
                                     blockIdx.y * 128);
}

// ---------------- merged prep: x convert+transpose, weight prep, M32 zero ----
__global__ __launch_bounds__(256) void k_prep2(
    const float* x, const float* Wq, const float* Wk, const float* Wv,
    const float* Wo, unsigned short* xb, unsigned short* xT,
    unsigned short* WqC, unsigned short* WkT, unsigned short* WvT,
    unsigned short* WoT, float* M32) {
    __shared__ unsigned short T[64][65];
    int tr = threadIdx.x >> 4, tc4 = (threadIdx.x & 15) * 4;
    int bid = blockIdx.x;
    if (bid >= 1280) {  // zero M32: 8 blocks x 256 thr x 32 floats = 65536
        size_t g = ((size_t)(bid - 1280) * 256 + threadIdx.x) * 32;
        float4 z4 = make_float4(0.f, 0.f, 0.f, 0.f);
#pragma unroll
        for (int q = 0; q < 8; ++q) *(float4*)(M32 + g + q * 4) = z4;
        return;
    }
    if (bid < 1024) {
        int b = bid >> 9, r = bid & 511;
        int d0 = (r & 7) * 64, l0 = (r >> 3) * 64;
        const float* xp = x + (size_t)b * LDIM * DIN;
        unsigned short* xbp = xb + (size_t)b * LDIM * DIN;
#pragma unroll
        for (int p = 0; p < 4; ++p) {
            int l = p * 16 + tr;
            float4 v = *(const float4*)(xp + (size_t)(l0 + l) * DIN + d0 + tc4);
            unsigned short q0 = f2bf(v.x), q1 = f2bf(v.y), q2 = f2bf(v.z),
                           q3 = f2bf(v.w);
            *(ushort4*)(xbp + (size_t)(l0 + l) * DIN + d0 + tc4) =
                make_ushort4(q0, q1, q2, q3);
            T[l][tc4 + 0] = q0; T[l][tc4 + 1] = q1;
            T[l][tc4 + 2] = q2; T[l][tc4 + 3] = q3;
        }
        __syncthreads();
        unsigned short* xTp = xT + (size_t)b * DIN * LDIM;
#pragma unroll
        for (int p = 0; p < 4; ++p) {
            int d = p * 16 + tr;
            ushort4 u = make_ushort4(T[tc4 + 0][d], T[tc4 + 1][d], T[tc4 + 2][d],
                                     T[tc4 + 3][d]);
            *(ushort4*)(xTp + (size_t)(d0 + d) * LDIM + l0 + tc4) = u;
        }
        return;
    }
    int p_ = bid - 1024;
    int t = p_ & 7, job = (p_ >> 3) & 3, h = p_ >> 5;
    if (job == 0) {
        const float* src = Wq + (size_t)h * DIN * DK;
#pragma unroll
        for (int p = 0; p < 4; ++p) {
            int i = t * 64 + p * 16 + tr;
            float4 v = *(const float4*)(src + (size_t)i * DK + tc4);
            *(ushort4*)(WqC + (size_t)i * (HDIM * DK) + h * DK + tc4) =
                make_ushort4(f2bf(v.x), f2bf(v.y), f2bf(v.z), f2bf(v.w));
        }
        return;
    }
    const float* src;
    unsigned short* dst;
    int rows, cols, r0, c0;
    if (job == 1) {
        src = Wk + (size_t)h * DIN * DK; dst = WkT + (size_t)h * DK * DIN;
        rows = DIN; cols = DK; r0 = t * 64; c0 = 0;
    } else if (job == 2) {
        src = Wv + (size_t)h * DIN * DV; dst = WvT + (size_t)h * DV * DIN;
        rows = DIN; cols = DV; r0 = t * 64; c0 = 0;
    } else {
        src = Wo + (size_t)h * DV * DOUT; dst = WoT + (size_t)h * DOUT * DV;
        rows = DV; cols = DOUT; r0 = 0; c0 = t * 64;
    }
#pragma unroll
    for (int p = 0; p < 4; ++p) {
        int r = p * 16 + tr;
        float4 v = *(const float4*)(src + (size_t)(r0 + r) * cols + c0 + tc4);
        T[r][tc4 + 0] = f2bf(v.x); T[r][tc4 + 1] = f2bf(v.y);
        T[r][tc4 + 2] = f2bf(v.z); T[r][tc4 + 3] = f2bf(v.w);
    }
    __syncthreads();
#pragma unroll
    for (int p = 0; p < 4; ++p) {
        int c = p * 16 + tr;
        ushort4 u = make_ushort4(T[tc4 + 0][c], T[tc4 + 1][c], T[tc4 + 2][c],
                                 T[tc4 + 3][c]);
        *(ushort4*)(dst + (size_t)(c0 + c) * rows + r0 + tc4) = u;
    }
}

extern "C" void kernel_launch(void* const* d_in, const int* in_sizes, int n_in,
                              void* d_out, int out_size, void* d_ws, size_t ws_size,
                              hipStream_t stream) {
    const float* x  = (const float*)d_in[0];
    const float* Wq = (const float*)d_in[1];
    const float* Wk = (const float*)d_in[2];
    const float* Wv = (const float*)d_in[3];
    const float* Wo = (const float*)d_in[4];
    float* out = (float*)d_out;

    unsigned short* w = (unsigned short*)d_ws;
    unsigned short* xb16  = w; w += (size_t)BDIM * LDIM * DIN;
    unsigned short* xT16  = w; w += (size_t)BDIM * DIN * LDIM;
    unsigned short* WqC   = w; w += (size_t)DIN * HDIM * DK;
    unsigned short* WkT   = w; w += (size_t)HDIM * DK * DIN;
    unsigned short* WvT   = w; w += (size_t)HDIM * DV * DIN;
    unsigned short* WoT   = w; w += (size_t)HDIM * DOUT * DV;
    unsigned short* G16   = w; w += (size_t)BDIM * DIN * DIN;
    unsigned short* CT    = w; w += (size_t)BDIM * DIN * DOUT;
    unsigned short* Gp    = w; w += (size_t)BDIM * NS * DIN * DIN;
    float* M32 = (float*)(((uintptr_t)w + 255) & ~(uintptr_t)255);  // 65536 f32

    k_prep2<<<dim3(1288), 256, 0, stream>>>(x, Wq, Wk, Wv, Wo, xb16, xT16,
                                            WqC, WkT, WvT, WoT, M32);
    k_gram<<<dim3(4, 4, BDIM * NS), 256, 0, stream>>>((const bf16_t*)xT16, Gp);
    k_gred<<<dim3((BDIM * DIN * DIN) / (256 * 8)), 256, 0, stream>>>(Gp, G16);
    k_proj<<<dim3(8, 8, BDIM), 256, 0, stream>>>((const bf16_t*)G16,
                                                 (const bf16_t*)WvT,
                                                 (const bf16_t*)WkT, M32);
    k_tail<<<dim3(8, 8, BDIM), 256, 0, stream>>>((const bf16_t*)WqC,
                                                 (const bf16_t*)WoT, M32, CT);
    k_out<<<dim3(LDIM / 64, DOUT / 128, BDIM), 256, 0, stream>>>(
        (const bf16_t*)xb16, (const bf16_t*)CT, out);
}

// Round 8
// 128.202 us; speedup vs baseline: 2.5018x; 1.0024x over previous
//
#include <hip/hip_runtime.h>
#include <cstdint>

// out[b] = x[b] @ C[b],  C[b] = sum_h Wq[h] M[b,h] Wo[h],
// M[b,h] = (x Wk[h])^T (x Wv[h])   [== Wk^T (x^T x) Wv, Gram eliminated]
// R8: 5 kernels. KV^T = (x @ [Wk|Wv]_cat)^T stored l-contiguous; M via
// split-K fp32 atomics; no x transpose, no Gram partials, no gred.

#define BDIM 2
#define LDIM 4096
#define DIN 512
#define HDIM 8
#define DK 64
#define DV 64
#define DOUT 512
#define MSPLIT 8  // split-K slices for M

using bf16_t = __bf16;
typedef __bf16 bf16x8 __attribute__((ext_vector_type(8)));
typedef float floatx4 __attribute__((ext_vector_type(4)));

__device__ __forceinline__ unsigned short f2bf(float f) {
    unsigned int u = __builtin_bit_cast(unsigned int, f);
    u += 0x7FFFu + ((u >> 16) & 1u);
    return (unsigned short)(u >> 16);
}

__device__ __forceinline__ void gld_lds16(const void* g, void* l) {
    __builtin_amdgcn_global_load_lds(
        (const __attribute__((address_space(1))) void*)g,
        (__attribute__((address_space(3))) void*)l, 16, 0, 0);
}

// ---------------- generic TN MFMA GEMM core ----------------
// C[m][n] = sum_k A[m][k]*B[n][k]; A,B k-contiguous bf16. 256 thr, 2x2 waves.
// OUT_MODE: 0 = f32 store, 1 = bf16 store, 2 = f32 atomicAdd.
template <int BM, int BN, int BK, bool TRANS_OUT, int OUT_MODE>
__device__ __forceinline__ void gemm_core(const bf16_t* A, const bf16_t* B,
                                          void* Cp, int K, int lda, int ldb,
                                          int ldc, int tm, int tn) {
    constexpr int WM = BM / 2, WN = BN / 2;
    constexpr int FM = WM / 16, FN = WN / 16;
    constexpr int CPR = BK / 8;  // 16B chunks per row
    __shared__ bf16_t As[BM * BK];
    __shared__ bf16_t Bs[BN * BK];
    const int tid = threadIdx.x;
    const int lane = tid & 63;
    const int wr = (tid >> 7) & 1;
    const int wc = (tid >> 6) & 1;

    A += (size_t)tm * lda;
    B += (size_t)tn * ldb;

    floatx4 acc[FM][FN] = {};

    for (int k0 = 0; k0 < K; k0 += BK) {
#pragma unroll
        for (int i = 0; i < (BM * CPR) / 256; ++i) {
            int c = i * 256 + tid;
            int m = c / CPR, kc = c % CPR;
            gld_lds16(A + (size_t)m * lda + k0 + kc * 8, As + c * 8);
        }
#pragma unroll
        for (int i = 0; i < (BN * CPR) / 256; ++i) {
            int c = i * 256 + tid;
            int m = c / CPR, kc = c % CPR;
            gld_lds16(B + (size_t)m * ldb + k0 + kc * 8, Bs + c * 8);
        }
        __syncthreads();

#pragma unroll
        for (int kk = 0; kk < BK; kk += 32) {
            bf16x8 aF[FM], bF[FN];
#pragma unroll
            for (int fm = 0; fm < FM; ++fm)
                aF[fm] = *(const bf16x8*)(As + (wr * WM + fm * 16 + (lane & 15)) * BK +
                                          kk + (lane >> 4) * 8);
#pragma unroll
            for (int fn = 0; fn < FN; ++fn)
                bF[fn] = *(const bf16x8*)(Bs + (wc * WN + fn * 16 + (lane & 15)) * BK +
                                          kk + (lane >> 4) * 8);
#pragma unroll
            for (int fm = 0; fm < FM; ++fm)
#pragma unroll
                for (int fn = 0; fn < FN; ++fn)
                    acc[fm][fn] = __builtin_amdgcn_mfma_f32_16x16x32_bf16(
                        aF[fm], bF[fn], acc[fm][fn], 0, 0, 0);
        }
        __syncthreads();
    }

    const int cr4 = (lane >> 4) * 4;
    const int cn = lane & 15;
#pragma unroll
    for (int fm = 0; fm < FM; ++fm)
#pragma unroll
        for (int fn = 0; fn < FN; ++fn)
#pragma unroll
            for (int r = 0; r < 4; ++r) {
                int m = tm + wr * WM + fm * 16 + cr4 + r;
                int n = tn + wc * WN + fn * 16 + cn;
                size_t idx = TRANS_OUT ? ((size_t)n * ldc + m)
                                       : ((size_t)m * ldc + n);
                if (OUT_MODE == 0)
                    ((float*)Cp)[idx] = acc[fm][fn][r];
                else if (OUT_MODE == 1)
                    ((unsigned short*)Cp)[idx] = f2bf(acc[fm][fn][r]);
                else
                    atomicAdd(&((float*)Cp)[idx], acc[fm][fn][r]);
            }
}

// ---- k_kv: KVT[b][n][l] = sum_j x[b][l][j] * WkvT[n][j]  (n in [0,1024)) ----
__global__ __launch_bounds__(256) void k_kv(const bf16_t* xb16, const bf16_t* WkvT,
                                            unsigned short* KVT) {
    int b = blockIdx.z;
    gemm_core<128, 128, 64, true, 1>(xb16 + (size_t)b * LDIM * DIN, WkvT,
                                     KVT + (size_t)b * 1024 * LDIM, DIN, DIN,
                                     DIN, LDIM, blockIdx.x * 128,
                                     blockIdx.y * 128);
}

// ---- k_msplit: M32[b,h][dk][v] += sum_l K[dk][l]*V[v][l] over slice ----
__global__ __launch_bounds__(256) void k_msplit(const bf16_t* KVT, float* M32) {
    int s = blockIdx.x, z = blockIdx.y, b = z >> 3, h = z & 7;
    const bf16_t* base = KVT + (size_t)b * 1024 * LDIM + s * (LDIM / MSPLIT);
    const bf16_t* A = base + (size_t)(h * 64) * LDIM;          // K rows
    const bf16_t* B = base + (size_t)(512 + h * 64) * LDIM;    // V rows
    gemm_core<64, 64, 64, false, 2>(A, B, M32 + (size_t)z * DK * DV,
                                    LDIM / MSPLIT, LDIM, LDIM, DV, 0, 0);
}

// ---- k_tail: CT[b][o][i] = sum_h sum_dk PT[h][o][dk] * Wq[h][i][dk]
//      where PT[h][o][dk] = sum_v WoT[h][o][v] * M[b,h][dk][v]
__global__ __launch_bounds__(256) void k_tail(const bf16_t* WqC, const bf16_t* WoT,
                                              const float* M32, unsigned short* CT) {
    int i0 = blockIdx.x * 64, o0 = blockIdx.y * 64, b = blockIdx.z;
    __shared__ bf16_t Aq[64 * 64];   // Wq rows i, k=dk
    __shared__ bf16_t Ws[64 * 64];   // WoT rows o, k=v
    __shared__ bf16_t Msh[64 * 64];  // M rows dk, k=v
    __shared__ bf16_t PTs[64 * 64];  // PT rows o, k=dk
    const int tid = threadIdx.x;
    const int lane = tid & 63;
    const int wr = (tid >> 7) & 1, wc = (tid >> 6) & 1;
    const int cr4 = (lane >> 4) * 4, cn = lane & 15;

    floatx4 acc[2][2] = {};

    for (int h = 0; h < HDIM; ++h) {
#pragma unroll
        for (int i = 0; i < 2; ++i) {
            int c = i * 256 + tid, m = c >> 3, kc = c & 7;
            gld_lds16(WqC + (size_t)(i0 + m) * DIN + h * 64 + kc * 8, Aq + c * 8);
            gld_lds16(WoT + ((size_t)h * DOUT + o0 + m) * DV + kc * 8, Ws + c * 8);
        }
        const float* Mh = M32 + ((size_t)(b * HDIM + h)) * (DK * DV);
#pragma unroll
        for (int i = 0; i < 4; ++i) {
            int idx = (i * 256 + tid) * 4;
            float4 v = *(const float4*)(Mh + idx);
            *(ushort4*)((unsigned short*)Msh + idx) =
                make_ushort4(f2bf(v.x), f2bf(v.y), f2bf(v.z), f2bf(v.w));
        }
        __syncthreads();

        // MFMA1: PT[o][dk] = sum_v Ws[o][v] * Msh[dk][v]
        floatx4 pt[2][2] = {};
#pragma unroll
        for (int kk = 0; kk < 64; kk += 32) {
            bf16x8 aF[2], bF[2];
#pragma unroll
            for (int f = 0; f < 2; ++f) {
                aF[f] = *(const bf16x8*)(Ws + (wr * 32 + f * 16 + cn) * 64 + kk +
                                         (lane >> 4) * 8);
                bF[f] = *(const bf16x8*)(Msh + (wc * 32 + f * 16 + cn) * 64 + kk +
                                         (lane >> 4) * 8);
            }
#pragma unroll
            for (int fm = 0; fm < 2; ++fm)
#pragma unroll
                for (int fn = 0; fn < 2; ++fn)
                    pt[fm][fn] = __builtin_amdgcn_mfma_f32_16x16x32_bf16(
                        aF[fm], bF[fn], pt[fm][fn], 0, 0, 0);
        }
#pragma unroll
        for (int fm = 0; fm < 2; ++fm)
#pragma unroll
            for (int fn = 0; fn < 2; ++fn)
#pragma unroll
                for (int r = 0; r < 4; ++r) {
                    int m = wr * 32 + fm * 16 + cr4 + r;
                    int n = wc * 32 + fn * 16 + cn;
                    ((unsigned short*)PTs)[m * 64 + n] = f2bf(pt[fm][fn][r]);
                }
        __syncthreads();

        // MFMA2: acc[o][i] += sum_dk PTs[o][dk] * Aq[i][dk]
#pragma unroll
        for (int kk = 0; kk < 64; kk += 32) {
            bf16x8 aF[2], bF[2];
#pragma unroll
            for (int f = 0; f < 2; ++f) {
                aF[f] = *(const bf16x8*)(PTs + (wr * 32 + f * 16 + cn) * 64 + kk +
                                         (lane >> 4) * 8);
                bF[f] = *(const bf16x8*)(Aq + (wc * 32 + f * 16 + cn) * 64 + kk +
                                         (lane >> 4) * 8);
            }
#pragma unroll
            for (int fm = 0; fm < 2; ++fm)
#pragma unroll
                for (int fn = 0; fn < 2; ++fn)
                    acc[fm][fn] = __builtin_amdgcn_mfma_f32_16x16x32_bf16(
                        aF[fm], bF[fn], acc[fm][fn], 0, 0, 0);
        }
        __syncthreads();
    }

    unsigned short* CTb = CT + (size_t)b * DIN * DOUT;
#pragma unroll
    for (int fm = 0; fm < 2; ++fm)
#pragma unroll
        for (int fn = 0; fn < 2; ++fn)
#pragma unroll
            for (int r = 0; r < 4; ++r) {
                int m = wr * 32 + fm * 16 + cr4 + r;
                int n = wc * 32 + fn * 16 + cn;
                CTb[(size_t)(o0 + m) * DIN + i0 + n] = f2bf(acc[fm][fn][r]);
            }
}

// ---- out[b] = x16[b] @ C[b], fp32 out, 64x128 tiles ----
__global__ __launch_bounds__(256) void k_out(const bf16_t* x16, const bf16_t* CT,
                                             float* out) {
    int b = blockIdx.z;
    gemm_core<64, 128, 64, false, 0>(x16 + (size_t)b * LDIM * DIN,
                                     CT + (size_t)b * DIN * DOUT,
                                     out + (size_t)b * LDIM * DOUT, DIN, DIN,
                                     DIN, DOUT, blockIdx.x * 64,
                                     blockIdx.y * 128);
}

// ---------------- prep: x convert (no transpose!), weights, M32 zero ----
// blocks [0,2048): x fp32->bf16, 8 elems/thread, 16B stores
// blocks [2048,2304): weight jobs (8 t x 4 jobs x 8 h)
// blocks [2304,2312): zero M32
__global__ __launch_bounds__(256) void k_prep2(
    const float* x, const float* Wq, const float* Wk, const float* Wv,
    const float* Wo, unsigned short* xb, unsigned short* WqC,
    unsigned short* WkvT, unsigned short* WoT, float* M32) {
    __shared__ unsigned short T[64][65];
    int tr = threadIdx.x >> 4, tc4 = (threadIdx.x & 15) * 4;
    int bid = blockIdx.x;
    if (bid < 2048) {
        size_t base = ((size_t)bid * 256 + threadIdx.x) * 8;
        float4 v0 = *(const float4*)(x + base);
        float4 v1 = *(const float4*)(x + base + 4);
        unsigned short o[8] = {f2bf(v0.x), f2bf(v0.y), f2bf(v0.z), f2bf(v0.w),
                               f2bf(v1.x), f2bf(v1.y), f2bf(v1.z), f2bf(v1.w)};
        *(uint4*)(xb + base) = *(const uint4*)o;
        return;
    }
    if (bid >= 2304) {  // zero M32: 8 blocks x 256 thr x 32 floats = 65536
        size_t g = ((size_t)(bid - 2304) * 256 + threadIdx.x) * 32;
        float4 z4 = make_float4(0.f, 0.f, 0.f, 0.f);
#pragma unroll
        for (int q = 0; q < 8; ++q) *(float4*)(M32 + g + q * 4) = z4;
        return;
    }
    int p_ = bid - 2048;
    int t = p_ & 7, job = (p_ >> 3) & 3, h = p_ >> 5;
    if (job == 0) {
        const float* src = Wq + (size_t)h * DIN * DK;
#pragma unroll
        for (int p = 0; p < 4; ++p) {
            int i = t * 64 + p * 16 + tr;
            float4 v = *(const float4*)(src + (size_t)i * DK + tc4);
            *(ushort4*)(WqC + (size_t)i * (HDIM * DK) + h * DK + tc4) =
                make_ushort4(f2bf(v.x), f2bf(v.y), f2bf(v.z), f2bf(v.w));
        }
        return;
    }
    const float* src;
    unsigned short* dst;
    int rows, cols, r0, c0;
    if (job == 1) {  // Wk[h] (512x64) -> WkvT rows [h*64, h*64+64)
        src = Wk + (size_t)h * DIN * DK; dst = WkvT + (size_t)(h * 64) * DIN;
        rows = DIN; cols = DK; r0 = t * 64; c0 = 0;
    } else if (job == 2) {  // Wv[h] -> WkvT rows [512 + h*64, ...)
        src = Wv + (size_t)h * DIN * DV; dst = WkvT + (size_t)(512 + h * 64) * DIN;
        rows = DIN; cols = DV; r0 = t * 64; c0 = 0;
    } else {  // Wo[h] (64x512) -> WoT[h] (512x64)
        src = Wo + (size_t)h * DV * DOUT; dst = WoT + (size_t)h * DOUT * DV;
        rows = DV; cols = DOUT; r0 = 0; c0 = t * 64;
    }
#pragma unroll
    for (int p = 0; p < 4; ++p) {
        int r = p * 16 + tr;
        float4 v = *(const float4*)(src + (size_t)(r0 + r) * cols + c0 + tc4);
        T[r][tc4 + 0] = f2bf(v.x); T[r][tc4 + 1] = f2bf(v.y);
        T[r][tc4 + 2] = f2bf(v.z); T[r][tc4 + 3] = f2bf(v.w);
    }
    __syncthreads();
#pragma unroll
    for (int p = 0; p < 4; ++p) {
        int c = p * 16 + tr;
        ushort4 u = make_ushort4(T[tc4 + 0][c], T[tc4 + 1][c], T[tc4 + 2][c],
                                 T[tc4 + 3][c]);
        *(ushort4*)(dst + (size_t)(c0 + c) * rows + r0 + tc4) = u;
    }
}

extern "C" void kernel_launch(void* const* d_in, const int* in_sizes, int n_in,
                              void* d_out, int out_size, void* d_ws, size_t ws_size,
                              hipStream_t stream) {
    const float* x  = (const float*)d_in[0];
    const float* Wq = (const float*)d_in[1];
    const float* Wk = (const float*)d_in[2];
    const float* Wv = (const float*)d_in[3];
    const float* Wo = (const float*)d_in[4];
    float* out = (float*)d_out;

    unsigned short* w = (unsigned short*)d_ws;
    unsigned short* xb16  = w; w += (size_t)BDIM * LDIM * DIN;   // 8.4 MB
    unsigned short* WqC   = w; w += (size_t)DIN * HDIM * DK;
    unsigned short* WkvT  = w; w += (size_t)1024 * DIN;
    unsigned short* WoT   = w; w += (size_t)HDIM * DOUT * DV;
    unsigned short* KVT   = w; w += (size_t)BDIM * 1024 * LDIM;  // 16.8 MB
    unsigned short* CT    = w; w += (size_t)BDIM * DIN * DOUT;
    float* M32 = (float*)(((uintptr_t)w + 255) & ~(uintptr_t)255);  // 65536 f32

    k_prep2<<<dim3(2312), 256, 0, stream>>>(x, Wq, Wk, Wv, Wo, xb16, WqC,
                                            WkvT, WoT, M32);
    k_kv<<<dim3(32, 8, BDIM), 256, 0, stream>>>((const bf16_t*)xb16,
                                                (const bf16_t*)WkvT, KVT);
    k_msplit<<<dim3(MSPLIT, BDIM * HDIM), 256, 0, stream>>>((const bf16_t*)KVT,
                                                            M32);
    k_tail<<<dim3(8, 8, BDIM), 256, 0, stream>>>((const bf16_t*)WqC,
                                                 (const bf16_t*)WoT, M32, CT);
    k_out<<<dim3(LDIM / 64, DOUT / 128, BDIM), 256, 0, stream>>>(
        (const bf16_t*)xb16, (const bf16_t*)CT, out);
}

// Round 9
// 124.602 us; speedup vs baseline: 2.5741x; 1.0289x over previous
//
#include <hip/hip_runtime.h>
#include <cstdint>

// out[b] = x[b] @ C[b],  C[b] = sum_h Wq[h] M[b,h] Wo[h],
// M[b,h] = (x Wk[h])^T (x Wv[h])
// R9: k_kv epilogue bounces the 128x128 tile through padded LDS and emits
// coalesced 16B stores along l (was: 2-byte scalar stores at 8KB stride ->
// L2 RMW amplification). MSPLIT 8->16.

#define BDIM 2
#define LDIM 4096
#define DIN 512
#define HDIM 8
#define DK 64
#define DV 64
#define DOUT 512
#define MSPLIT 16  // split-K slices for M

using bf16_t = __bf16;
typedef __bf16 bf16x8 __attribute__((ext_vector_type(8)));
typedef float floatx4 __attribute__((ext_vector_type(4)));

__device__ __forceinline__ unsigned short f2bf(float f) {
    unsigned int u = __builtin_bit_cast(unsigned int, f);
    u += 0x7FFFu + ((u >> 16) & 1u);
    return (unsigned short)(u >> 16);
}

__device__ __forceinline__ void gld_lds16(const void* g, void* l) {
    __builtin_amdgcn_global_load_lds(
        (const __attribute__((address_space(1))) void*)g,
        (__attribute__((address_space(3))) void*)l, 16, 0, 0);
}

// ---------------- generic TN MFMA GEMM core ----------------
// C[m][n] = sum_k A[m][k]*B[n][k]; A,B k-contiguous bf16. 256 thr, 2x2 waves.
// OUT_MODE: 0 = f32 store, 1 = bf16 store, 2 = f32 atomicAdd,
//           3 = bf16 transposed store via padded-LDS bounce (coalesced 16B).
template <int BM, int BN, int BK, bool TRANS_OUT, int OUT_MODE>
__device__ __forceinline__ void gemm_core(const bf16_t* A, const bf16_t* B,
                                          void* Cp, int K, int lda, int ldb,
                                          int ldc, int tm, int tn) {
    constexpr int WM = BM / 2, WN = BN / 2;
    constexpr int FM = WM / 16, FN = WN / 16;
    constexpr int CPR = BK / 8;  // 16B chunks per row
    constexpr int EP_STRIDE = BM + 4;  // padded epilogue row stride (mode 3)
    constexpr int SMEM_ELEMS =
        (OUT_MODE == 3) ? ((BN * EP_STRIDE > (BM + BN) * BK) ? BN * EP_STRIDE
                                                             : (BM + BN) * BK)
                        : (BM + BN) * BK;
    __shared__ bf16_t smem[SMEM_ELEMS];
    bf16_t* As = smem;
    bf16_t* Bs = smem + BM * BK;
    const int tid = threadIdx.x;
    const int lane = tid & 63;
    const int wr = (tid >> 7) & 1;
    const int wc = (tid >> 6) & 1;

    A += (size_t)tm * lda;
    B += (size_t)tn * ldb;

    floatx4 acc[FM][FN] = {};

    for (int k0 = 0; k0 < K; k0 += BK) {
#pragma unroll
        for (int i = 0; i < (BM * CPR) / 256; ++i) {
            int c = i * 256 + tid;
            int m = c / CPR, kc = c % CPR;
            gld_lds16(A + (size_t)m * lda + k0 + kc * 8, As + c * 8);
        }
#pragma unroll
        for (int i = 0; i < (BN * CPR) / 256; ++i) {
            int c = i * 256 + tid;
            int m = c / CPR, kc = c % CPR;
            gld_lds16(B + (size_t)m * ldb + k0 + kc * 8, Bs + c * 8);
        }
        __syncthreads();

#pragma unroll
        for (int kk = 0; kk < BK; kk += 32) {
            bf16x8 aF[FM], bF[FN];
#pragma unroll
            for (int fm = 0; fm < FM; ++fm)
                aF[fm] = *(const bf16x8*)(As + (wr * WM + fm * 16 + (lane & 15)) * BK +
                                          kk + (lane >> 4) * 8);
#pragma unroll
            for (int fn = 0; fn < FN; ++fn)
                bF[fn] = *(const bf16x8*)(Bs + (wc * WN + fn * 16 + (lane & 15)) * BK +
                                          kk + (lane >> 4) * 8);
#pragma unroll
            for (int fm = 0; fm < FM; ++fm)
#pragma unroll
                for (int fn = 0; fn < FN; ++fn)
                    acc[fm][fn] = __builtin_amdgcn_mfma_f32_16x16x32_bf16(
                        aF[fm], bF[fn], acc[fm][fn], 0, 0, 0);
        }
        __syncthreads();
    }

    const int cr4 = (lane >> 4) * 4;
    const int cn = lane & 15;

    if (OUT_MODE == 3) {
        // write acc into padded LDS as [n][m], m-contiguous
#pragma unroll
        for (int fm = 0; fm < FM; ++fm)
#pragma unroll
            for (int fn = 0; fn < FN; ++fn)
#pragma unroll
                for (int r = 0; r < 4; ++r) {
                    int m = wr * WM + fm * 16 + cr4 + r;
                    int n = wc * WN + fn * 16 + cn;
                    ((unsigned short*)smem)[n * EP_STRIDE + m] =
                        f2bf(acc[fm][fn][r]);
                }
        __syncthreads();
        // coalesced copy-out: rows n, 16B chunks along m
        constexpr int CPERROW = BM / 8;
#pragma unroll
        for (int i = 0; i < (BM * BN) / (8 * 256); ++i) {
            int c = i * 256 + tid;
            int row = c / CPERROW;
            int col = (c % CPERROW) * 8;
            *(uint4*)((unsigned short*)Cp + (size_t)(tn + row) * ldc + tm + col) =
                *(const uint4*)((const unsigned short*)smem + row * EP_STRIDE + col);
        }
        return;
    }

#pragma unroll
    for (int fm = 0; fm < FM; ++fm)
#pragma unroll
        for (int fn = 0; fn < FN; ++fn)
#pragma unroll
            for (int r = 0; r < 4; ++r) {
                int m = tm + wr * WM + fm * 16 + cr4 + r;
                int n = tn + wc * WN + fn * 16 + cn;
                size_t idx = TRANS_OUT ? ((size_t)n * ldc + m)
                                       : ((size_t)m * ldc + n);
                if (OUT_MODE == 0)
                    ((float*)Cp)[idx] = acc[fm][fn][r];
                else if (OUT_MODE == 1)
                    ((unsigned short*)Cp)[idx] = f2bf(acc[fm][fn][r]);
                else
                    atomicAdd(&((float*)Cp)[idx], acc[fm][fn][r]);
            }
}

// ---- k_kv: KVT[b][n][l] = sum_j x[b][l][j] * WkvT[n][j]  (n in [0,1024)) ----
__global__ __launch_bounds__(256) void k_kv(const bf16_t* xb16, const bf16_t* WkvT,
                                            unsigned short* KVT) {
    int b = blockIdx.z;
    gemm_core<128, 128, 64, true, 3>(xb16 + (size_t)b * LDIM * DIN, WkvT,
                                     KVT + (size_t)b * 1024 * LDIM, DIN, DIN,
                                     DIN, LDIM, blockIdx.x * 128,
                                     blockIdx.y * 128);
}

// ---- k_msplit: M32[b,h][dk][v] += sum_l K[dk][l]*V[v][l] over slice ----
__global__ __launch_bounds__(256) void k_msplit(const bf16_t* KVT, float* M32) {
    int s = blockIdx.x, z = blockIdx.y, b = z >> 3, h = z & 7;
    const bf16_t* base = KVT + (size_t)b * 1024 * LDIM + s * (LDIM / MSPLIT);
    const bf16_t* A = base + (size_t)(h * 64) * LDIM;          // K rows
    const bf16_t* B = base + (size_t)(512 + h * 64) * LDIM;    // V rows
    gemm_core<64, 64, 64, false, 2>(A, B, M32 + (size_t)z * DK * DV,
                                    LDIM / MSPLIT, LDIM, LDIM, DV, 0, 0);
}

// ---- k_tail: CT[b][o][i] = sum_h sum_dk PT[h][o][dk] * Wq[h][i][dk]
//      where PT[h][o][dk] = sum_v WoT[h][o][v] * M[b,h][dk][v]
__global__ __launch_bounds__(256) void k_tail(const bf16_t* WqC, const bf16_t* WoT,
                                              const float* M32, unsigned short* CT) {
    int i0 = blockIdx.x * 64, o0 = blockIdx.y * 64, b = blockIdx.z;
    __shared__ bf16_t Aq[64 * 64];
    __shared__ bf16_t Ws[64 * 64];
    __shared__ bf16_t Msh[64 * 64];
    __shared__ bf16_t PTs[64 * 64];
    const int tid = threadIdx.x;
    const int lane = tid & 63;
    const int wr = (tid >> 7) & 1, wc = (tid >> 6) & 1;
    const int cr4 = (lane >> 4) * 4, cn = lane & 15;

    floatx4 acc[2][2] = {};

    for (int h = 0; h < HDIM; ++h) {
#pragma unroll
        for (int i = 0; i < 2; ++i) {
            int c = i * 256 + tid, m = c >> 3, kc = c & 7;
            gld_lds16(WqC + (size_t)(i0 + m) * DIN + h * 64 + kc * 8, Aq + c * 8);
            gld_lds16(WoT + ((size_t)h * DOUT + o0 + m) * DV + kc * 8, Ws + c * 8);
        }
        const float* Mh = M32 + ((size_t)(b * HDIM + h)) * (DK * DV);
#pragma unroll
        for (int i = 0; i < 4; ++i) {
            int idx = (i * 256 + tid) * 4;
            float4 v = *(const float4*)(Mh + idx);
            *(ushort4*)((unsigned short*)Msh + idx) =
                make_ushort4(f2bf(v.x), f2bf(v.y), f2bf(v.z), f2bf(v.w));
        }
        __syncthreads();

        // MFMA1: PT[o][dk] = sum_v Ws[o][v] * Msh[dk][v]
        floatx4 pt[2][2] = {};
#pragma unroll
        for (int kk = 0; kk < 64; kk += 32) {
            bf16x8 aF[2], bF[2];
#pragma unroll
            for (int f = 0; f < 2; ++f) {
                aF[f] = *(const bf16x8*)(Ws + (wr * 32 + f * 16 + cn) * 64 + kk +
                                         (lane >> 4) * 8);
                bF[f] = *(const bf16x8*)(Msh + (wc * 32 + f * 16 + cn) * 64 + kk +
                                         (lane >> 4) * 8);
            }
#pragma unroll
            for (int fm = 0; fm < 2; ++fm)
#pragma unroll
                for (int fn = 0; fn < 2; ++fn)
                    pt[fm][fn] = __builtin_amdgcn_mfma_f32_16x16x32_bf16(
                        aF[fm], bF[fn], pt[fm][fn], 0, 0, 0);
        }
#pragma unroll
        for (int fm = 0; fm < 2; ++fm)
#pragma unroll
            for (int fn = 0; fn < 2; ++fn)
#pragma unroll
                for (int r = 0; r < 4; ++r) {
                    int m = wr * 32 + fm * 16 + cr4 + r;
                    int n = wc * 32 + fn * 16 + cn;
                    ((unsigned short*)PTs)[m * 64 + n] = f2bf(pt[fm][fn][r]);
                }
        __syncthreads();

        // MFMA2: acc[o][i] += sum_dk PTs[o][dk] * Aq[i][dk]
#pragma unroll
        for (int kk = 0; kk < 64; kk += 32) {
            bf16x8 aF[2], bF[2];
#pragma unroll
            for (int f = 0; f < 2; ++f) {
                aF[f] = *(const bf16x8*)(PTs + (wr * 32 + f * 16 + cn) * 64 + kk +
                                         (lane >> 4) * 8);
                bF[f] = *(const bf16x8*)(Aq + (wc * 32 + f * 16 + cn) * 64 + kk +
                                         (lane >> 4) * 8);
            }
#pragma unroll
            for (int fm = 0; fm < 2; ++fm)
#pragma unroll
                for (int fn = 0; fn < 2; ++fn)
                    acc[fm][fn] = __builtin_amdgcn_mfma_f32_16x16x32_bf16(
                        aF[fm], bF[fn], acc[fm][fn], 0, 0, 0);
        }
        __syncthreads();
    }

    unsigned short* CTb = CT + (size_t)b * DIN * DOUT;
#pragma unroll
    for (int fm = 0; fm < 2; ++fm)
#pragma unroll
        for (int fn = 0; fn < 2; ++fn)
#pragma unroll
            for (int r = 0; r < 4; ++r) {
                int m = wr * 32 + fm * 16 + cr4 + r;
                int n = wc * 32 + fn * 16 + cn;
                CTb[(size_t)(o0 + m) * DIN + i0 + n] = f2bf(acc[fm][fn][r]);
            }
}

// ---- out[b] = x16[b] @ C[b], fp32 out, 64x128 tiles ----
__global__ __launch_bounds__(256) void k_out(const bf16_t* x16, const bf16_t* CT,
                                             float* out) {
    int b = blockIdx.z;
    gemm_core<64, 128, 64, false, 0>(x16 + (size_t)b * LDIM * DIN,
                                     CT + (size_t)b * DIN * DOUT,
                                     out + (size_t)b * LDIM * DOUT, DIN, DIN,
                                     DIN, DOUT, blockIdx.x * 64,
                                     blockIdx.y * 128);
}

// ---------------- prep: x convert, weights, M32 zero ----
__global__ __launch_bounds__(256) void k_prep2(
    const float* x, const float* Wq, const float* Wk, const float* Wv,
    const float* Wo, unsigned short* xb, unsigned short* WqC,
    unsigned short* WkvT, unsigned short* WoT, float* M32) {
    __shared__ unsigned short T[64][65];
    int tr = threadIdx.x >> 4, tc4 = (threadIdx.x & 15) * 4;
    int bid = blockIdx.x;
    if (bid < 2048) {
        size_t base = ((size_t)bid * 256 + threadIdx.x) * 8;
        float4 v0 = *(const float4*)(x + base);
        float4 v1 = *(const float4*)(x + base + 4);
        unsigned short o[8] = {f2bf(v0.x), f2bf(v0.y), f2bf(v0.z), f2bf(v0.w),
                               f2bf(v1.x), f2bf(v1.y), f2bf(v1.z), f2bf(v1.w)};
        *(uint4*)(xb + base) = *(const uint4*)o;
        return;
    }
    if (bid >= 2304) {  // zero M32
        size_t g = ((size_t)(bid - 2304) * 256 + threadIdx.x) * 32;
        float4 z4 = make_float4(0.f, 0.f, 0.f, 0.f);
#pragma unroll
        for (int q = 0; q < 8; ++q) *(float4*)(M32 + g + q * 4) = z4;
        return;
    }
    int p_ = bid - 2048;
    int t = p_ & 7, job = (p_ >> 3) & 3, h = p_ >> 5;
    if (job == 0) {
        const float* src = Wq + (size_t)h * DIN * DK;
#pragma unroll
        for (int p = 0; p < 4; ++p) {
            int i = t * 64 + p * 16 + tr;
            float4 v = *(const float4*)(src + (size_t)i * DK + tc4);
            *(ushort4*)(WqC + (size_t)i * (HDIM * DK) + h * DK + tc4) =
                make_ushort4(f2bf(v.x), f2bf(v.y), f2bf(v.z), f2bf(v.w));
        }
        return;
    }
    const float* src;
    unsigned short* dst;
    int rows, cols, r0, c0;
    if (job == 1) {
        src = Wk + (size_t)h * DIN * DK; dst = WkvT + (size_t)(h * 64) * DIN;
        rows = DIN; cols = DK; r0 = t * 64; c0 = 0;
    } else if (job == 2) {
        src = Wv + (size_t)h * DIN * DV; dst = WkvT + (size_t)(512 + h * 64) * DIN;
        rows = DIN; cols = DV; r0 = t * 64; c0 = 0;
    } else {
        src = Wo + (size_t)h * DV * DOUT; dst = WoT + (size_t)h * DOUT * DV;
        rows = DV; cols = DOUT; r0 = 0; c0 = t * 64;
    }
#pragma unroll
    for (int p = 0; p < 4; ++p) {
        int r = p * 16 + tr;
        float4 v = *(const float4*)(src + (size_t)(r0 + r) * cols + c0 + tc4);
        T[r][tc4 + 0] = f2bf(v.x); T[r][tc4 + 1] = f2bf(v.y);
        T[r][tc4 + 2] = f2bf(v.z); T[r][tc4 + 3] = f2bf(v.w);
    }
    __syncthreads();
#pragma unroll
    for (int p = 0; p < 4; ++p) {
        int c = p * 16 + tr;
        ushort4 u = make_ushort4(T[tc4 + 0][c], T[tc4 + 1][c], T[tc4 + 2][c],
                                 T[tc4 + 3][c]);
        *(ushort4*)(dst + (size_t)(c0 + c) * rows + r0 + tc4) = u;
    }
}

extern "C" void kernel_launch(void* const* d_in, const int* in_sizes, int n_in,
                              void* d_out, int out_size, void* d_ws, size_t ws_size,
                              hipStream_t stream) {
    const float* x  = (const float*)d_in[0];
    const float* Wq = (const float*)d_in[1];
    const float* Wk = (const float*)d_in[2];
    const float* Wv = (const float*)d_in[3];
    const float* Wo = (const float*)d_in[4];
    float* out = (float*)d_out;

    unsigned short* w = (unsigned short*)d_ws;
    unsigned short* xb16  = w; w += (size_t)BDIM * LDIM * DIN;   // 8.4 MB
    unsigned short* WqC   = w; w += (size_t)DIN * HDIM * DK;
    unsigned short* WkvT  = w; w += (size_t)1024 * DIN;
    unsigned short* WoT   = w; w += (size_t)HDIM * DOUT * DV;
    unsigned short* KVT   = w; w += (size_t)BDIM * 1024 * LDIM;  // 16.8 MB
    unsigned short* CT    = w; w += (size_t)BDIM * DIN * DOUT;
    float* M32 = (float*)(((uintptr_t)w + 255) & ~(uintptr_t)255);  // 65536 f32

    k_prep2<<<dim3(2312), 256, 0, stream>>>(x, Wq, Wk, Wv, Wo, xb16, WqC,
                                            WkvT, WoT, M32);
    k_kv<<<dim3(32, 8, BDIM), 256, 0, stream>>>((const bf16_t*)xb16,
                                                (const bf16_t*)WkvT, KVT);
    k_msplit<<<dim3(MSPLIT, BDIM * HDIM), 256, 0, stream>>>((const bf16_t*)KVT,
                                                            M32);
    k_tail<<<dim3(8, 8, BDIM), 256, 0, stream>>>((const bf16_t*)WqC,
                                                 (const bf16_t*)WoT, M32, CT);
    k_out<<<dim3(LDIM / 64, DOUT / 128, BDIM), 256, 0, stream>>>(
        (const bf16_t*)xb16, (const bf16_t*)CT, out);
}

// Round 10
// 123.535 us; speedup vs baseline: 2.5964x; 1.0086x over previous
//
#include <hip/hip_runtime.h>
#include <cstdint>

// out[b] = x[b] @ C[b],  C[b] = sum_h Wq[h] M[b,h] Wo[h],
// M[b,h] = (x Wk[h])^T (x Wv[h])
// R10: 4 kernels. Wkv columns interleaved per head ([K_h|V_h] = one 128-wide
// n-tile), so each k_kvm block computes its K/V tile, bounces it through LDS,
// contracts K^T V in-block and atomicAdds fp32 M partials. K/V never hit
// global memory; k_msplit and the 16.8MB KVT round-trip are gone.

#define BDIM 2
#define LDIM 4096
#define DIN 512
#define HDIM 8
#define DK 64
#define DV 64
#define DOUT 512

using bf16_t = __bf16;
typedef __bf16 bf16x8 __attribute__((ext_vector_type(8)));
typedef float floatx4 __attribute__((ext_vector_type(4)));

__device__ __forceinline__ unsigned short f2bf(float f) {
    unsigned int u = __builtin_bit_cast(unsigned int, f);
    u += 0x7FFFu + ((u >> 16) & 1u);
    return (unsigned short)(u >> 16);
}

__device__ __forceinline__ void gld_lds16(const void* g, void* l) {
    __builtin_amdgcn_global_load_lds(
        (const __attribute__((address_space(1))) void*)g,
        (__attribute__((address_space(3))) void*)l, 16, 0, 0);
}

// ---------------- generic TN MFMA GEMM core (modes 0/1) ----------------
template <int BM, int BN, int BK, bool TRANS_OUT, int OUT_MODE>
__device__ __forceinline__ void gemm_core(const bf16_t* A, const bf16_t* B,
                                          void* Cp, int K, int lda, int ldb,
                                          int ldc, int tm, int tn) {
    constexpr int WM = BM / 2, WN = BN / 2;
    constexpr int FM = WM / 16, FN = WN / 16;
    constexpr int CPR = BK / 8;
    __shared__ bf16_t As[BM * BK];
    __shared__ bf16_t Bs[BN * BK];
    const int tid = threadIdx.x;
    const int lane = tid & 63;
    const int wr = (tid >> 7) & 1;
    const int wc = (tid >> 6) & 1;

    A += (size_t)tm * lda;
    B += (size_t)tn * ldb;

    floatx4 acc[FM][FN] = {};

    for (int k0 = 0; k0 < K; k0 += BK) {
#pragma unroll
        for (int i = 0; i < (BM * CPR) / 256; ++i) {
            int c = i * 256 + tid;
            int m = c / CPR, kc = c % CPR;
            gld_lds16(A + (size_t)m * lda + k0 + kc * 8, As + c * 8);
        }
#pragma unroll
        for (int i = 0; i < (BN * CPR) / 256; ++i) {
            int c = i * 256 + tid;
            int m = c / CPR, kc = c % CPR;
            gld_lds16(B + (size_t)m * ldb + k0 + kc * 8, Bs + c * 8);
        }
        __syncthreads();

#pragma unroll
        for (int kk = 0; kk < BK; kk += 32) {
            bf16x8 aF[FM], bF[FN];
#pragma unroll
            for (int fm = 0; fm < FM; ++fm)
                aF[fm] = *(const bf16x8*)(As + (wr * WM + fm * 16 + (lane & 15)) * BK +
                                          kk + (lane >> 4) * 8);
#pragma unroll
            for (int fn = 0; fn < FN; ++fn)
                bF[fn] = *(const bf16x8*)(Bs + (wc * WN + fn * 16 + (lane & 15)) * BK +
                                          kk + (lane >> 4) * 8);
#pragma unroll
            for (int fm = 0; fm < FM; ++fm)
#pragma unroll
                for (int fn = 0; fn < FN; ++fn)
                    acc[fm][fn] = __builtin_amdgcn_mfma_f32_16x16x32_bf16(
                        aF[fm], bF[fn], acc[fm][fn], 0, 0, 0);
        }
        __syncthreads();
    }

    const int cr4 = (lane >> 4) * 4;
    const int cn = lane & 15;
#pragma unroll
    for (int fm = 0; fm < FM; ++fm)
#pragma unroll
        for (int fn = 0; fn < FN; ++fn)
#pragma unroll
            for (int r = 0; r < 4; ++r) {
                int m = tm + wr * WM + fm * 16 + cr4 + r;
                int n = tn + wc * WN + fn * 16 + cn;
                size_t idx = TRANS_OUT ? ((size_t)n * ldc + m)
                                       : ((size_t)m * ldc + n);
                if (OUT_MODE == 0)
                    ((float*)Cp)[idx] = acc[fm][fn][r];
                else
                    ((unsigned short*)Cp)[idx] = f2bf(acc[fm][fn][r]);
            }
}

// ---- k_kvm: per (l-tile 128, head, b):
//   KV_tile[l][n] = x_tile @ Wkv_head  (n = [K_h(64) | V_h(64)], K=512)
//   -> LDS [n][l] (pad 136) -> M_contrib[dk][v] = sum_l K[dk][l]*V[v][l]
//   -> atomicAdd fp32 into M32[b,h]
__global__ __launch_bounds__(256) void k_kvm(const bf16_t* xb16,
                                             const bf16_t* WkvT, float* M32) {
    constexpr int EP = 136;  // padded row stride (272B = 16B-aligned rows)
    __shared__ bf16_t smem[128 * EP];  // 34.8 KB; aliases staging
    bf16_t* As = smem;
    bf16_t* Bs = smem + 128 * 64;
    const int lt = blockIdx.x, h = blockIdx.y, b = blockIdx.z;
    const int tid = threadIdx.x;
    const int lane = tid & 63;
    const int wr = (tid >> 7) & 1, wc = (tid >> 6) & 1;
    const int cr4 = (lane >> 4) * 4, cn = lane & 15;

    const bf16_t* A = xb16 + (size_t)b * LDIM * DIN + (size_t)lt * 128 * DIN;
    const bf16_t* B = WkvT + (size_t)h * 128 * DIN;

    floatx4 acc[4][4] = {};
    for (int k0 = 0; k0 < DIN; k0 += 64) {
#pragma unroll
        for (int i = 0; i < 4; ++i) {
            int c = i * 256 + tid, m = c >> 3, kc = c & 7;
            gld_lds16(A + (size_t)m * DIN + k0 + kc * 8, As + c * 8);
        }
#pragma unroll
        for (int i = 0; i < 4; ++i) {
            int c = i * 256 + tid, m = c >> 3, kc = c & 7;
            gld_lds16(B + (size_t)m * DIN + k0 + kc * 8, Bs + c * 8);
        }
        __syncthreads();
#pragma unroll
        for (int kk = 0; kk < 64; kk += 32) {
            bf16x8 aF[4], bF[4];
#pragma unroll
            for (int fm = 0; fm < 4; ++fm)
                aF[fm] = *(const bf16x8*)(As + (wr * 64 + fm * 16 + cn) * 64 +
                                          kk + (lane >> 4) * 8);
#pragma unroll
            for (int fn = 0; fn < 4; ++fn)
                bF[fn] = *(const bf16x8*)(Bs + (wc * 64 + fn * 16 + cn) * 64 +
                                          kk + (lane >> 4) * 8);
#pragma unroll
            for (int fm = 0; fm < 4; ++fm)
#pragma unroll
                for (int fn = 0; fn < 4; ++fn)
                    acc[fm][fn] = __builtin_amdgcn_mfma_f32_16x16x32_bf16(
                        aF[fm], bF[fn], acc[fm][fn], 0, 0, 0);
        }
        __syncthreads();
    }

    // KV tile -> LDS as [n][l], l-contiguous, padded stride EP
#pragma unroll
    for (int fm = 0; fm < 4; ++fm)
#pragma unroll
        for (int fn = 0; fn < 4; ++fn)
#pragma unroll
            for (int r = 0; r < 4; ++r) {
                int m = wr * 64 + fm * 16 + cr4 + r;  // l local
                int n = wc * 64 + fn * 16 + cn;       // dk|v
                ((unsigned short*)smem)[n * EP + m] = f2bf(acc[fm][fn][r]);
            }
    __syncthreads();

    // M_contrib[dk][v] = sum_l Ks[dk][l] * Vs[v][l]   (K = 128 l-values)
    floatx4 mm[2][2] = {};
#pragma unroll
    for (int kk = 0; kk < 128; kk += 32) {
        bf16x8 aF[2], bF[2];
#pragma unroll
        for (int f = 0; f < 2; ++f) {
            aF[f] = *(const bf16x8*)(smem + (wr * 32 + f * 16 + cn) * EP + kk +
                                     (lane >> 4) * 8);
            bF[f] = *(const bf16x8*)(smem + (64 + wc * 32 + f * 16 + cn) * EP +
                                     kk + (lane >> 4) * 8);
        }
#pragma unroll
        for (int fm = 0; fm < 2; ++fm)
#pragma unroll
            for (int fn = 0; fn < 2; ++fn)
                mm[fm][fn] = __builtin_amdgcn_mfma_f32_16x16x32_bf16(
                    aF[fm], bF[fn], mm[fm][fn], 0, 0, 0);
    }
    float* Mh = M32 + ((size_t)(b * HDIM + h)) * (DK * DV);
#pragma unroll
    for (int fm = 0; fm < 2; ++fm)
#pragma unroll
        for (int fn = 0; fn < 2; ++fn)
#pragma unroll
            for (int r = 0; r < 4; ++r) {
                int dk = wr * 32 + fm * 16 + cr4 + r;
                int v = wc * 32 + fn * 16 + cn;
                atomicAdd(&Mh[dk * 64 + v], mm[fm][fn][r]);
            }
}

// ---- k_tail: CT[b][o][i] = sum_h sum_dk PT[h][o][dk] * Wq[h][i][dk]
//      where PT[h][o][dk] = sum_v WoT[h][o][v] * M[b,h][dk][v]
__global__ __launch_bounds__(256) void k_tail(const bf16_t* WqC, const bf16_t* WoT,
                                              const float* M32, unsigned short* CT) {
    int i0 = blockIdx.x * 64, o0 = blockIdx.y * 64, b = blockIdx.z;
    __shared__ bf16_t Aq[64 * 64];
    __shared__ bf16_t Ws[64 * 64];
    __shared__ bf16_t Msh[64 * 64];
    __shared__ bf16_t PTs[64 * 64];
    const int tid = threadIdx.x;
    const int lane = tid & 63;
    const int wr = (tid >> 7) & 1, wc = (tid >> 6) & 1;
    const int cr4 = (lane >> 4) * 4, cn = lane & 15;

    floatx4 acc[2][2] = {};

    for (int h = 0; h < HDIM; ++h) {
#pragma unroll
        for (int i = 0; i < 2; ++i) {
            int c = i * 256 + tid, m = c >> 3, kc = c & 7;
            gld_lds16(WqC + (size_t)(i0 + m) * DIN + h * 64 + kc * 8, Aq + c * 8);
            gld_lds16(WoT + ((size_t)h * DOUT + o0 + m) * DV + kc * 8, Ws + c * 8);
        }
        const float* Mh = M32 + ((size_t)(b * HDIM + h)) * (DK * DV);
#pragma unroll
        for (int i = 0; i < 4; ++i) {
            int idx = (i * 256 + tid) * 4;
            float4 v = *(const float4*)(Mh + idx);
            *(ushort4*)((unsigned short*)Msh + idx) =
                make_ushort4(f2bf(v.x), f2bf(v.y), f2bf(v.z), f2bf(v.w));
        }
        __syncthreads();

        floatx4 pt[2][2] = {};
#pragma unroll
        for (int kk = 0; kk < 64; kk += 32) {
            bf16x8 aF[2], bF[2];
#pragma unroll
            for (int f = 0; f < 2; ++f) {
                aF[f] = *(const bf16x8*)(Ws + (wr * 32 + f * 16 + cn) * 64 + kk +
                                         (lane >> 4) * 8);
                bF[f] = *(const bf16x8*)(Msh + (wc * 32 + f * 16 + cn) * 64 + kk +
                                         (lane >> 4) * 8);
            }
#pragma unroll
            for (int fm = 0; fm < 2; ++fm)
#pragma unroll
                for (int fn = 0; fn < 2; ++fn)
                    pt[fm][fn] = __builtin_amdgcn_mfma_f32_16x16x32_bf16(
                        aF[fm], bF[fn], pt[fm][fn], 0, 0, 0);
        }
#pragma unroll
        for (int fm = 0; fm < 2; ++fm)
#pragma unroll
            for (int fn = 0; fn < 2; ++fn)
#pragma unroll
                for (int r = 0; r < 4; ++r) {
                    int m = wr * 32 + fm * 16 + cr4 + r;
                    int n = wc * 32 + fn * 16 + cn;
                    ((unsigned short*)PTs)[m * 64 + n] = f2bf(pt[fm][fn][r]);
                }
        __syncthreads();

#pragma unroll
        for (int kk = 0; kk < 64; kk += 32) {
            bf16x8 aF[2], bF[2];
#pragma unroll
            for (int f = 0; f < 2; ++f) {
                aF[f] = *(const bf16x8*)(PTs + (wr * 32 + f * 16 + cn) * 64 + kk +
                                         (lane >> 4) * 8);
                bF[f] = *(const bf16x8*)(Aq + (wc * 32 + f * 16 + cn) * 64 + kk +
                                         (lane >> 4) * 8);
            }
#pragma unroll
            for (int fm = 0; fm < 2; ++fm)
#pragma unroll
                for (int fn = 0; fn < 2; ++fn)
                    acc[fm][fn] = __builtin_amdgcn_mfma_f32_16x16x32_bf16(
                        aF[fm], bF[fn], acc[fm][fn], 0, 0, 0);
        }
        __syncthreads();
    }

    unsigned short* CTb = CT + (size_t)b * DIN * DOUT;
#pragma unroll
    for (int fm = 0; fm < 2; ++fm)
#pragma unroll
        for (int fn = 0; fn < 2; ++fn)
#pragma unroll
            for (int r = 0; r < 4; ++r) {
                int m = wr * 32 + fm * 16 + cr4 + r;
                int n = wc * 32 + fn * 16 + cn;
                CTb[(size_t)(o0 + m) * DIN + i0 + n] = f2bf(acc[fm][fn][r]);
            }
}

// ---- out[b] = x16[b] @ C[b], fp32 out, 64x128 tiles ----
__global__ __launch_bounds__(256) void k_out(const bf16_t* x16, const bf16_t* CT,
                                             float* out) {
    int b = blockIdx.z;
    gemm_core<64, 128, 64, false, 0>(x16 + (size_t)b * LDIM * DIN,
                                     CT + (size_t)b * DIN * DOUT,
                                     out + (size_t)b * LDIM * DOUT, DIN, DIN,
                                     DIN, DOUT, blockIdx.x * 64,
                                     blockIdx.y * 128);
}

// ---------------- prep: x convert, weights (Wkv interleaved), M32 zero ----
__global__ __launch_bounds__(256) void k_prep2(
    const float* x, const float* Wq, const float* Wk, const float* Wv,
    const float* Wo, unsigned short* xb, unsigned short* WqC,
    unsigned short* WkvT, unsigned short* WoT, float* M32) {
    __shared__ unsigned short T[64][65];
    int tr = threadIdx.x >> 4, tc4 = (threadIdx.x & 15) * 4;
    int bid = blockIdx.x;
    if (bid < 2048) {
        size_t base = ((size_t)bid * 256 + threadIdx.x) * 8;
        float4 v0 = *(const float4*)(x + base);
        float4 v1 = *(const float4*)(x + base + 4);
        unsigned short o[8] = {f2bf(v0.x), f2bf(v0.y), f2bf(v0.z), f2bf(v0.w),
                               f2bf(v1.x), f2bf(v1.y), f2bf(v1.z), f2bf(v1.w)};
        *(uint4*)(xb + base) = *(const uint4*)o;
        return;
    }
    if (bid >= 2304) {  // zero M32
        size_t g = ((size_t)(bid - 2304) * 256 + threadIdx.x) * 32;
        float4 z4 = make_float4(0.f, 0.f, 0.f, 0.f);
#pragma unroll
        for (int q = 0; q < 8; ++q) *(float4*)(M32 + g + q * 4) = z4;
        return;
    }
    int p_ = bid - 2048;
    int t = p_ & 7, job = (p_ >> 3) & 3, h = p_ >> 5;
    if (job == 0) {
        const float* src = Wq + (size_t)h * DIN * DK;
#pragma unroll
        for (int p = 0; p < 4; ++p) {
            int i = t * 64 + p * 16 + tr;
            float4 v = *(const float4*)(src + (size_t)i * DK + tc4);
            *(ushort4*)(WqC + (size_t)i * (HDIM * DK) + h * DK + tc4) =
                make_ushort4(f2bf(v.x), f2bf(v.y), f2bf(v.z), f2bf(v.w));
        }
        return;
    }
    const float* src;
    unsigned short* dst;
    int rows, cols, r0, c0;
    if (job == 1) {  // Wk[h] -> WkvT rows [h*128, h*128+64)
        src = Wk + (size_t)h * DIN * DK;
        dst = WkvT + ((size_t)h * 128) * DIN;
        rows = DIN; cols = DK; r0 = t * 64; c0 = 0;
    } else if (job == 2) {  // Wv[h] -> WkvT rows [h*128+64, h*128+128)
        src = Wv + (size_t)h * DIN * DV;
        dst = WkvT + ((size_t)h * 128 + 64) * DIN;
        rows = DIN; cols = DV; r0 = t * 64; c0 = 0;
    } else {  // Wo[h] (64x512) -> WoT[h] (512x64)
        src = Wo + (size_t)h * DV * DOUT;
        dst = WoT + (size_t)h * DOUT * DV;
        rows = DV; cols = DOUT; r0 = 0; c0 = t * 64;
    }
#pragma unroll
    for (int p = 0; p < 4; ++p) {
        int r = p * 16 + tr;
        float4 v = *(const float4*)(src + (size_t)(r0 + r) * cols + c0 + tc4);
        T[r][tc4 + 0] = f2bf(v.x); T[r][tc4 + 1] = f2bf(v.y);
        T[r][tc4 + 2] = f2bf(v.z); T[r][tc4 + 3] = f2bf(v.w);
    }
    __syncthreads();
#pragma unroll
    for (int p = 0; p < 4; ++p) {
        int c = p * 16 + tr;
        ushort4 u = make_ushort4(T[tc4 + 0][c], T[tc4 + 1][c], T[tc4 + 2][c],
                                 T[tc4 + 3][c]);
        *(ushort4*)(dst + (size_t)(c0 + c) * rows + r0 + tc4) = u;
    }
}

extern "C" void kernel_launch(void* const* d_in, const int* in_sizes, int n_in,
                              void* d_out, int out_size, void* d_ws, size_t ws_size,
                              hipStream_t stream) {
    const float* x  = (const float*)d_in[0];
    const float* Wq = (const float*)d_in[1];
    const float* Wk = (const float*)d_in[2];
    const float* Wv = (const float*)d_in[3];
    const float* Wo = (const float*)d_in[4];
    float* out = (float*)d_out;

    unsigned short* w = (unsigned short*)d_ws;
    unsigned short* xb16  = w; w += (size_t)BDIM * LDIM * DIN;   // 8.4 MB
    unsigned short* WqC   = w; w += (size_t)DIN * HDIM * DK;
    unsigned short* WkvT  = w; w += (size_t)1024 * DIN;
    unsigned short* WoT   = w; w += (size_t)HDIM * DOUT * DV;
    unsigned short* CT    = w; w += (size_t)BDIM * DIN * DOUT;
    float* M32 = (float*)(((uintptr_t)w + 255) & ~(uintptr_t)255);  // 65536 f32

    k_prep2<<<dim3(2312), 256, 0, stream>>>(x, Wq, Wk, Wv, Wo, xb16, WqC,
                                            WkvT, WoT, M32);
    k_kvm<<<dim3(LDIM / 128, HDIM, BDIM), 256, 0, stream>>>(
        (const bf16_t*)xb16, (const bf16_t*)WkvT, M32);
    k_tail<<<dim3(8, 8, BDIM), 256, 0, stream>>>((const bf16_t*)WqC,
                                                 (const bf16_t*)WoT, M32, CT);
    k_out<<<dim3(LDIM / 64, DOUT / 128, BDIM), 256, 0, stream>>>(
        (const bf16_t*)xb16, (const bf16_t*)CT, out);
}